// Round 1
// baseline (5409.429 us; speedup 1.0000x reference)
//
#include <hip/hip_runtime.h>
#include <math.h>

// ---- static problem dims ----
constexpr int B   = 4;
constexpr int S   = 501;        // 500 patches + cls
constexpr int T   = B * S;      // 2004 token rows
constexpr int DM  = 256;        // d_model
constexpr int DI  = 512;        // mamba inner dim
constexpr int DH  = 1024;       // 2*DI
constexpr int NST = 16;         // d_state
constexpr int RDT = 32;         // dt_rank
constexpr int LAYERS = 8;

__device__ __forceinline__ float silu_f(float x) { return x / (1.0f + expf(-x)); }
__device__ __forceinline__ float softplus_f(float x) { return x > 20.0f ? x : log1pf(expf(x)); }

// ---------------- patch embed: strided conv as GEMM with LDS-staged input ----------------
// grid (50, B), 256 threads. Each block: 10 patches for one b, thread = out channel.
__global__ __launch_bounds__(256)
void patch_k(const float* __restrict__ x, const float* __restrict__ pw,
             const float* __restrict__ pb, float* __restrict__ h)
{
    __shared__ float xs[129 * 100];
    const int tc = blockIdx.x, b = blockIdx.y;
    const int tid = threadIdx.x;
    const int col0 = tc * 100;
    for (int i = tid; i < 129 * 100; i += 256) {
        int c = i / 100, j = i - c * 100;
        xs[i] = x[(long)b * 129 * 5000 + (long)c * 5000 + col0 + j];
    }
    __syncthreads();
    const int o = tid;
    float bias = pb[o];
    float acc[10];
#pragma unroll
    for (int it = 0; it < 10; ++it) acc[it] = bias;
    for (int c = 0; c < 129; ++c) {
#pragma unroll
        for (int k = 0; k < 10; ++k) {
            float w = pw[(long)o * 1290 + c * 10 + k];
#pragma unroll
            for (int it = 0; it < 10; ++it)
                acc[it] = fmaf(w, xs[c * 100 + it * 10 + k], acc[it]);
        }
    }
    long base = ((long)b * S + 1 + tc * 10) * DM;
#pragma unroll
    for (int it = 0; it < 10; ++it)
        h[base + (long)it * DM + o] = acc[it];
}

// grid (B), 64 threads: write cls row
__global__ __launch_bounds__(64)
void cls_k(const float* __restrict__ cls, float* __restrict__ h)
{
    int b = blockIdx.x, lane = threadIdx.x;
    ((float4*)(h + (long)b * S * DM))[lane] = ((const float4*)cls)[lane];
}

// ---------------- layernorm over 256: one wave per row ----------------
// rowMul=1: per-token (grid T).  rowMul=S: final LN on cls rows only (grid B).
__global__ __launch_bounds__(64)
void ln_k(const float* __restrict__ hin, const float* __restrict__ g,
          const float* __restrict__ be, float* __restrict__ out, int rowMul)
{
    long hr = (long)blockIdx.x * rowMul;
    int lane = threadIdx.x;
    float4 v = ((const float4*)(hin + hr * DM))[lane];
    float s = v.x + v.y + v.z + v.w;
    float q = v.x * v.x + v.y * v.y + v.z * v.z + v.w * v.w;
#pragma unroll
    for (int off = 32; off; off >>= 1) { s += __shfl_xor(s, off); q += __shfl_xor(q, off); }
    float mean = s * (1.0f / DM);
    float var  = q * (1.0f / DM) - mean * mean;
    float rs = rsqrtf(var + 1e-5f);
    float4 gg = ((const float4*)g)[lane];
    float4 bb = ((const float4*)be)[lane];
    float4 o;
    o.x = (v.x - mean) * rs * gg.x + bb.x;
    o.y = (v.y - mean) * rs * gg.y + bb.y;
    o.z = (v.z - mean) * rs * gg.z + bb.z;
    o.w = (v.w - mean) * rs * gg.w + bb.w;
    ((float4*)(out + (long)blockIdx.x * DM))[lane] = o;
}

// ---------------- generic fp32 GEMM: C[m,n] = sum_k A[m,k]*W[n,k]  (+ epilogue) ----------------
// 64x64 tile, 256 threads, 4x4 per thread.  blockIdx.z selects direction (A/W/bias ptr pair).
// EPI: 0=plain store, 1=bias+softplus, 2=gate-cat (mamba out proj), 3=residual add
template<int EPI>
__global__ __launch_bounds__(256)
void gemm_k(const float* __restrict__ A0, const float* __restrict__ A1, int lda,
            const float* __restrict__ W0, const float* __restrict__ W1,
            const float* __restrict__ b0, const float* __restrict__ b1,
            float* __restrict__ Cout, long cStrideZ, int ldc,
            const float* __restrict__ resid,
            int M, int N, int K)
{
    const int dir = blockIdx.z;
    const float* __restrict__ A = dir ? A1 : A0;
    const float* __restrict__ W = dir ? W1 : W0;
    __shared__ float As[16][64];
    __shared__ float Ws[16][64];
    const int tid = threadIdx.x;
    const int tx = tid & 15, ty = tid >> 4;
    const int m0 = blockIdx.x * 64, n0 = blockIdx.y * 64;
    const int arow = tid >> 2;            // 0..63
    const int acol = (tid & 3) * 4;       // 0,4,8,12
    float acc[4][4] = {};

    for (int k0 = 0; k0 < K; k0 += 16) {
        {
            int row = m0 + arow;
            float4 va = make_float4(0.f, 0.f, 0.f, 0.f);
            if (row < M) va = *(const float4*)(A + (long)row * lda + k0 + acol);
            As[acol + 0][arow] = va.x; As[acol + 1][arow] = va.y;
            As[acol + 2][arow] = va.z; As[acol + 3][arow] = va.w;
            float4 vw = *(const float4*)(W + (long)(n0 + arow) * K + k0 + acol);
            Ws[acol + 0][arow] = vw.x; Ws[acol + 1][arow] = vw.y;
            Ws[acol + 2][arow] = vw.z; Ws[acol + 3][arow] = vw.w;
        }
        __syncthreads();
#pragma unroll
        for (int kk = 0; kk < 16; ++kk) {
            float4 av = *(const float4*)&As[kk][ty * 4];
            float4 wv = *(const float4*)&Ws[kk][tx * 4];
            float a[4] = {av.x, av.y, av.z, av.w};
            float w[4] = {wv.x, wv.y, wv.z, wv.w};
#pragma unroll
            for (int i = 0; i < 4; ++i)
#pragma unroll
                for (int j = 0; j < 4; ++j)
                    acc[i][j] = fmaf(a[i], w[j], acc[i][j]);
        }
        __syncthreads();
    }

    const float* bias = dir ? b1 : b0;
    float* C = Cout + (long)dir * cStrideZ;
#pragma unroll
    for (int i = 0; i < 4; ++i) {
        int row = m0 + ty * 4 + i;
        if (row >= M) continue;
        int col = n0 + tx * 4;
        if constexpr (EPI == 0) {
            float4 v = make_float4(acc[i][0], acc[i][1], acc[i][2], acc[i][3]);
            *(float4*)(C + (long)row * ldc + col) = v;
        } else if constexpr (EPI == 1) {
            float4 b4 = *(const float4*)(bias + col);
            float4 v;
            v.x = softplus_f(acc[i][0] + b4.x);
            v.y = softplus_f(acc[i][1] + b4.y);
            v.z = softplus_f(acc[i][2] + b4.z);
            v.w = softplus_f(acc[i][3] + b4.w);
            *(float4*)(C + (long)row * ldc + col) = v;
        } else if constexpr (EPI == 2) {
            // mamba output proj -> gate with silu(res) and scatter into concat buffer
            int bb = row / S;
            int t  = row - bb * S;
            long rt = dir ? (long)(bb * S + (S - 1 - t)) : (long)row;
            float4 g4 = *(const float4*)(resid + rt * DH + DI + col);
            float4 v;
            v.x = acc[i][0] * silu_f(g4.x);
            v.y = acc[i][1] * silu_f(g4.y);
            v.z = acc[i][2] * silu_f(g4.z);
            v.w = acc[i][3] * silu_f(g4.w);
            *(float4*)(Cout + rt * DH + (dir ? DI : 0) + col) = v;
        } else {   // EPI == 3: residual add
            float4 r4 = *(const float4*)(resid + (long)row * ldc + col);
            float4 v;
            v.x = acc[i][0] + r4.x;
            v.y = acc[i][1] + r4.y;
            v.z = acc[i][2] + r4.z;
            v.w = acc[i][3] + r4.w;
            *(float4*)(C + (long)row * ldc + col) = v;
        }
    }
}

// ---------------- causal depthwise conv (K=4) + silu ----------------
// input: cols 0..511 of a 1024-stride buffer; output: 512-stride, optional reversed copy.
__global__ __launch_bounds__(256)
void conv_k(const float* __restrict__ in0, const float* __restrict__ in1,
            const float* __restrict__ cw0, const float* __restrict__ cw1,
            const float* __restrict__ cb0, const float* __restrict__ cb1,
            float* __restrict__ out, long outStrideZ, float* __restrict__ out_rev)
{
    const int dir = blockIdx.z;
    const float* __restrict__ in = dir ? in1 : in0;
    const float* __restrict__ cw = dir ? cw1 : cw0;
    const float* __restrict__ cb = dir ? cb1 : cb0;
    int idx = blockIdx.x * 256 + threadIdx.x;
    if (idx >= T * DI) return;
    int d = idx & (DI - 1);
    int r = idx >> 9;
    int b = r / S, t = r - b * S;
    float acc = cb[d];
#pragma unroll
    for (int k = 0; k < 4; ++k) {
        int tt = t - 3 + k;
        if (tt >= 0) acc = fmaf(cw[d * 4 + k], in[(long)(b * S + tt) * DH + d], acc);
    }
    acc = silu_f(acc);
    (out + (long)dir * outStrideZ)[(long)r * DI + d] = acc;
    if (out_rev) out_rev[(long)(b * S + (S - 1 - t)) * DI + d] = acc;
}

// ---------------- selective scan (both dirs), fused y+u*D and silu(z) gating ----------------
// grid (B, DI/16, 2), 256 threads: thread = (d_local, n); sequential over t.
__global__ __launch_bounds__(256)
void scan_k(const float* __restrict__ delta, const float* __restrict__ dtBC,
            const float* __restrict__ u, const float* __restrict__ xmz,
            const float* __restrict__ Al0, const float* __restrict__ Al1,
            const float* __restrict__ D0, const float* __restrict__ D1,
            float* __restrict__ p)
{
    const int dir = blockIdx.z;
    const int b = blockIdx.x;
    const int dblk = blockIdx.y;
    const int tid = threadIdx.x;
    const int n = tid & 15;
    const int d = dblk * 16 + (tid >> 4);
    const float* Al = dir ? Al1 : Al0;
    const float A = -expf(Al[d * NST + n]);
    const float Dp = (dir ? D1 : D0)[d];

    const float* dl = delta + (long)dir * T * DI + (long)b * S * DI;
    const float* bc = dtBC  + (long)dir * T * 64 + (long)b * S * 64;
    const float* uu = u     + (long)dir * T * DI + (long)b * S * DI;
    const float* zz = xmz   + (long)dir * T * DH + (long)b * S * DH + DI;
    float* po       = p     + (long)dir * T * DI + (long)b * S * DI;

    float h = 0.0f;
    for (int t = 0; t < S; ++t) {
        float dv = dl[(long)t * DI + d];
        float uv = uu[(long)t * DI + d];
        float Bv = bc[(long)t * 64 + RDT + n];
        float Cv = bc[(long)t * 64 + RDT + NST + n];
        float dA = expf(dv * A);
        h = fmaf(dA, h, dv * Bv * uv);
        float yc = h * Cv;
        yc += __shfl_xor(yc, 1);
        yc += __shfl_xor(yc, 2);
        yc += __shfl_xor(yc, 4);
        yc += __shfl_xor(yc, 8);
        if (n == 0) {
            float zv = zz[(long)t * DH + d];
            po[(long)t * DI + d] = (yc + uv * Dp) * silu_f(zv);
        }
    }
}

// ---------------- host orchestration ----------------
extern "C" void kernel_launch(void* const* d_in, const int* in_sizes, int n_in,
                              void* d_out, int out_size, void* d_ws, size_t ws_size,
                              hipStream_t stream)
{
    (void)in_sizes; (void)n_in; (void)out_size; (void)ws_size;
    const float* x        = (const float*)d_in[0];
    const float* patch_w  = (const float*)d_in[1];
    const float* patch_b  = (const float*)d_in[2];
    const float* cls_tok  = (const float*)d_in[3];
    const float* ln_g     = (const float*)d_in[4];
    const float* ln_b     = (const float*)d_in[5];
    const float* in_w     = (const float*)d_in[6];
    const float* cw       = (const float*)d_in[7];
    const float* cb       = (const float*)d_in[8];
    const float* out_w    = (const float*)d_in[9];
    const float* fn_g     = (const float*)d_in[10];
    const float* fn_b     = (const float*)d_in[11];
    const float* mf_in    = (const float*)d_in[12];
    const float* mf_cw    = (const float*)d_in[13];
    const float* mf_cb    = (const float*)d_in[14];
    const float* mf_xp    = (const float*)d_in[15];
    const float* mf_dtw   = (const float*)d_in[16];
    const float* mf_dtb   = (const float*)d_in[17];
    const float* mf_Al    = (const float*)d_in[18];
    const float* mf_D     = (const float*)d_in[19];
    const float* mf_ow    = (const float*)d_in[20];
    const float* mb_in    = (const float*)d_in[21];
    const float* mb_cw    = (const float*)d_in[22];
    const float* mb_cb    = (const float*)d_in[23];
    const float* mb_xp    = (const float*)d_in[24];
    const float* mb_dtw   = (const float*)d_in[25];
    const float* mb_dtb   = (const float*)d_in[26];
    const float* mb_Al    = (const float*)d_in[27];
    const float* mb_D     = (const float*)d_in[28];
    const float* mb_ow    = (const float*)d_in[29];

    float* ws = (float*)d_ws;
    float* h      = ws;                    // T*DM
    float* xn     = h     + (long)T * DM;  // T*DM
    float* xcres  = xn    + (long)T * DM;  // T*DH
    float* xc     = xcres + (long)T * DH;  // T*DI
    float* xcrev  = xc    + (long)T * DI;  // T*DI
    float* xmz    = xcrev + (long)T * DI;  // 2*T*DH
    float* u      = xmz   + 2L * T * DH;   // 2*T*DI
    float* dtBC   = u     + 2L * T * DI;   // 2*T*64
    float* delta  = dtBC  + 2L * T * 64;   // 2*T*DI
    float* pbuf   = delta + 2L * T * DI;   // 2*T*DI
    float* ycat   = pbuf  + 2L * T * DI;   // T*DH

    // patch embed + cls
    patch_k<<<dim3(50, B), 256, 0, stream>>>(x, patch_w, patch_b, h);
    cls_k<<<dim3(B), 64, 0, stream>>>(cls_tok, h);

    constexpr int GM = (T + 63) / 64;   // 32

    for (int l = 0; l < LAYERS; ++l) {
        const float* lng = ln_g + (long)l * DM;
        const float* lnb = ln_b + (long)l * DM;
        const float* inw = in_w + (long)l * DH * DM;
        const float* cwl = cw   + (long)l * DI * 4;
        const float* cbl = cb   + (long)l * DI;
        const float* oww = out_w + (long)l * DM * DH;
        const float* fin = mf_in + (long)l * DH * DI;
        const float* bin = mb_in + (long)l * DH * DI;
        const float* fcw = mf_cw + (long)l * DI * 4;
        const float* bcw = mb_cw + (long)l * DI * 4;
        const float* fcb = mf_cb + (long)l * DI;
        const float* bcb = mb_cb + (long)l * DI;
        const float* fxp = mf_xp + (long)l * (RDT + 2 * NST) * DI;
        const float* bxp = mb_xp + (long)l * (RDT + 2 * NST) * DI;
        const float* fdw = mf_dtw + (long)l * DI * RDT;
        const float* bdw = mb_dtw + (long)l * DI * RDT;
        const float* fdb = mf_dtb + (long)l * DI;
        const float* bdb = mb_dtb + (long)l * DI;
        const float* fAl = mf_Al + (long)l * DI * NST;
        const float* bAl = mb_Al + (long)l * DI * NST;
        const float* fD  = mf_D  + (long)l * DI;
        const float* bD  = mb_D  + (long)l * DI;
        const float* fow = mf_ow + (long)l * DI * DI;
        const float* bow = mb_ow + (long)l * DI * DI;

        // xn = LN(h)
        ln_k<<<dim3(T), 64, 0, stream>>>(h, lng, lnb, xn, 1);
        // xcres = xn @ in_w^T  (T x 1024)
        gemm_k<0><<<dim3(GM, DH / 64, 1), 256, 0, stream>>>(
            xn, xn, DM, inw, inw, nullptr, nullptr, xcres, 0, DH, nullptr, T, DH, DM);
        // xc = silu(dwconv(xcres[:, :512])) ; xcrev = time-reversed copy
        conv_k<<<dim3(T * DI / 256, 1, 1), 256, 0, stream>>>(
            xcres, xcres, cwl, cwl, cbl, cbl, xc, 0, xcrev);
        // xmz[dir] = (xc|xcrev) @ m{f,b}_in^T  (T x 1024)
        gemm_k<0><<<dim3(GM, DH / 64, 2), 256, 0, stream>>>(
            xc, xcrev, DI, fin, bin, nullptr, nullptr, xmz, (long)T * DH, DH, nullptr, T, DH, DI);
        // u[dir] = silu(dwconv(xmz[dir][:, :512]))
        conv_k<<<dim3(T * DI / 256, 1, 2), 256, 0, stream>>>(
            xmz, xmz + (long)T * DH, fcw, bcw, fcb, bcb, u, (long)T * DI, nullptr);
        // dtBC[dir] = u[dir] @ xp^T  (T x 64)
        gemm_k<0><<<dim3(GM, 1, 2), 256, 0, stream>>>(
            u, u + (long)T * DI, DI, fxp, bxp, nullptr, nullptr, dtBC, (long)T * 64, 64, nullptr,
            T, 64, DI);
        // delta[dir] = softplus(dt @ dtw^T + dtb)  (T x 512)
        gemm_k<1><<<dim3(GM, DI / 64, 2), 256, 0, stream>>>(
            dtBC, dtBC + (long)T * 64, 64, fdw, bdw, fdb, bdb, delta, (long)T * DI, DI, nullptr,
            T, DI, RDT);
        // p[dir] = (scan(u,delta,A,B,C) + u*D) * silu(z)
        scan_k<<<dim3(B, DI / 16, 2), 256, 0, stream>>>(
            delta, dtBC, u, xmz, fAl, bAl, fD, bD, pbuf);
        // ycat[:, dir*512:...] = (p[dir] @ ow^T) * silu(res), time-flipped back for dir=1
        gemm_k<2><<<dim3(GM, DI / 64, 2), 256, 0, stream>>>(
            pbuf, pbuf + (long)T * DI, DI, fow, bow, nullptr, nullptr, ycat, 0, DH, xcres,
            T, DI, DI);
        // h = ycat @ out_w^T + h
        gemm_k<3><<<dim3(GM, DM / 64, 1), 256, 0, stream>>>(
            ycat, ycat, DH, oww, oww, nullptr, nullptr, h, 0, DM, h, T, DM, DH);
    }

    // final LN on cls rows only -> d_out (4 x 256)
    ln_k<<<dim3(B), 64, 0, stream>>>(h, fn_g, fn_b, (float*)d_out, S);
}

// Round 2
// 3295.925 us; speedup vs baseline: 1.6412x; 1.6412x over previous
//
#include <hip/hip_runtime.h>
#include <math.h>

// ---- static problem dims ----
constexpr int B   = 4;
constexpr int S   = 501;        // 500 patches + cls
constexpr int T   = B * S;      // 2004 token rows
constexpr int DM  = 256;        // d_model
constexpr int DI  = 512;        // mamba inner dim
constexpr int DH  = 1024;       // 2*DI
constexpr int NST = 16;         // d_state
constexpr int RDT = 32;         // dt_rank
constexpr int LAYERS = 8;

__device__ __forceinline__ float silu_f(float x) { return x / (1.0f + expf(-x)); }
__device__ __forceinline__ float softplus_f(float x) { return x > 20.0f ? x : log1pf(expf(x)); }

// ---------------- patch embed: strided conv as GEMM with LDS-staged input ----------------
// grid (50, B), 256 threads. Each block: 10 patches for one b, thread = out channel.
__global__ __launch_bounds__(256)
void patch_k(const float* __restrict__ x, const float* __restrict__ pw,
             const float* __restrict__ pb, float* __restrict__ h)
{
    __shared__ float xs[129 * 100];
    const int tc = blockIdx.x, b = blockIdx.y;
    const int tid = threadIdx.x;
    const int col0 = tc * 100;
    for (int i = tid; i < 129 * 100; i += 256) {
        int c = i / 100, j = i - c * 100;
        xs[i] = x[(long)b * 129 * 5000 + (long)c * 5000 + col0 + j];
    }
    __syncthreads();
    const int o = tid;
    float bias = pb[o];
    float acc[10];
#pragma unroll
    for (int it = 0; it < 10; ++it) acc[it] = bias;
    for (int c = 0; c < 129; ++c) {
#pragma unroll
        for (int k = 0; k < 10; ++k) {
            float w = pw[(long)o * 1290 + c * 10 + k];
#pragma unroll
            for (int it = 0; it < 10; ++it)
                acc[it] = fmaf(w, xs[c * 100 + it * 10 + k], acc[it]);
        }
    }
    long base = ((long)b * S + 1 + tc * 10) * DM;
#pragma unroll
    for (int it = 0; it < 10; ++it)
        h[base + (long)it * DM + o] = acc[it];
}

// grid (B), 64 threads: write cls row
__global__ __launch_bounds__(64)
void cls_k(const float* __restrict__ cls, float* __restrict__ h)
{
    int b = blockIdx.x, lane = threadIdx.x;
    ((float4*)(h + (long)b * S * DM))[lane] = ((const float4*)cls)[lane];
}

// ---------------- layernorm over 256: one wave per row ----------------
// rowMul=1: per-token (grid T).  rowMul=S: final LN on cls rows only (grid B).
__global__ __launch_bounds__(64)
void ln_k(const float* __restrict__ hin, const float* __restrict__ g,
          const float* __restrict__ be, float* __restrict__ out, int rowMul)
{
    long hr = (long)blockIdx.x * rowMul;
    int lane = threadIdx.x;
    float4 v = ((const float4*)(hin + hr * DM))[lane];
    float s = v.x + v.y + v.z + v.w;
    float q = v.x * v.x + v.y * v.y + v.z * v.z + v.w * v.w;
#pragma unroll
    for (int off = 32; off; off >>= 1) { s += __shfl_xor(s, off); q += __shfl_xor(q, off); }
    float mean = s * (1.0f / DM);
    float var  = q * (1.0f / DM) - mean * mean;
    float rs = rsqrtf(var + 1e-5f);
    float4 gg = ((const float4*)g)[lane];
    float4 bb = ((const float4*)be)[lane];
    float4 o;
    o.x = (v.x - mean) * rs * gg.x + bb.x;
    o.y = (v.y - mean) * rs * gg.y + bb.y;
    o.z = (v.z - mean) * rs * gg.z + bb.z;
    o.w = (v.w - mean) * rs * gg.w + bb.w;
    ((float4*)(out + (long)blockIdx.x * DM))[lane] = o;
}

// ---------------- generic fp32 GEMM: C[m,n] = sum_k A[m,k]*W[n,k]  (+ epilogue) ----------------
// 64x64 tile, 256 threads, 4x4 per thread.  blockIdx.z selects direction (A/W/bias ptr pair).
// EPI: 0=plain store, 1=bias+softplus, 2=gate-cat (mamba out proj), 3=residual add
template<int EPI>
__global__ __launch_bounds__(256)
void gemm_k(const float* __restrict__ A0, const float* __restrict__ A1, int lda,
            const float* __restrict__ W0, const float* __restrict__ W1,
            const float* __restrict__ b0, const float* __restrict__ b1,
            float* __restrict__ Cout, long cStrideZ, int ldc,
            const float* __restrict__ resid,
            int M, int N, int K)
{
    const int dir = blockIdx.z;
    const float* __restrict__ A = dir ? A1 : A0;
    const float* __restrict__ W = dir ? W1 : W0;
    __shared__ float As[16][64];
    __shared__ float Ws[16][64];
    const int tid = threadIdx.x;
    const int tx = tid & 15, ty = tid >> 4;
    const int m0 = blockIdx.x * 64, n0 = blockIdx.y * 64;
    const int arow = tid >> 2;            // 0..63
    const int acol = (tid & 3) * 4;       // 0,4,8,12
    float acc[4][4] = {};

    for (int k0 = 0; k0 < K; k0 += 16) {
        {
            int row = m0 + arow;
            float4 va = make_float4(0.f, 0.f, 0.f, 0.f);
            if (row < M) va = *(const float4*)(A + (long)row * lda + k0 + acol);
            As[acol + 0][arow] = va.x; As[acol + 1][arow] = va.y;
            As[acol + 2][arow] = va.z; As[acol + 3][arow] = va.w;
            float4 vw = *(const float4*)(W + (long)(n0 + arow) * K + k0 + acol);
            Ws[acol + 0][arow] = vw.x; Ws[acol + 1][arow] = vw.y;
            Ws[acol + 2][arow] = vw.z; Ws[acol + 3][arow] = vw.w;
        }
        __syncthreads();
#pragma unroll
        for (int kk = 0; kk < 16; ++kk) {
            float4 av = *(const float4*)&As[kk][ty * 4];
            float4 wv = *(const float4*)&Ws[kk][tx * 4];
            float a[4] = {av.x, av.y, av.z, av.w};
            float w[4] = {wv.x, wv.y, wv.z, wv.w};
#pragma unroll
            for (int i = 0; i < 4; ++i)
#pragma unroll
                for (int j = 0; j < 4; ++j)
                    acc[i][j] = fmaf(a[i], w[j], acc[i][j]);
        }
        __syncthreads();
    }

    const float* bias = dir ? b1 : b0;
    float* C = Cout + (long)dir * cStrideZ;
#pragma unroll
    for (int i = 0; i < 4; ++i) {
        int row = m0 + ty * 4 + i;
        if (row >= M) continue;
        int col = n0 + tx * 4;
        if constexpr (EPI == 0) {
            float4 v = make_float4(acc[i][0], acc[i][1], acc[i][2], acc[i][3]);
            *(float4*)(C + (long)row * ldc + col) = v;
        } else if constexpr (EPI == 1) {
            float4 b4 = *(const float4*)(bias + col);
            float4 v;
            v.x = softplus_f(acc[i][0] + b4.x);
            v.y = softplus_f(acc[i][1] + b4.y);
            v.z = softplus_f(acc[i][2] + b4.z);
            v.w = softplus_f(acc[i][3] + b4.w);
            *(float4*)(C + (long)row * ldc + col) = v;
        } else if constexpr (EPI == 2) {
            // mamba output proj -> gate with silu(res) and scatter into concat buffer
            int bb = row / S;
            int t  = row - bb * S;
            long rt = dir ? (long)(bb * S + (S - 1 - t)) : (long)row;
            float4 g4 = *(const float4*)(resid + rt * DH + DI + col);
            float4 v;
            v.x = acc[i][0] * silu_f(g4.x);
            v.y = acc[i][1] * silu_f(g4.y);
            v.z = acc[i][2] * silu_f(g4.z);
            v.w = acc[i][3] * silu_f(g4.w);
            *(float4*)(Cout + rt * DH + (dir ? DI : 0) + col) = v;
        } else {   // EPI == 3: residual add
            float4 r4 = *(const float4*)(resid + (long)row * ldc + col);
            float4 v;
            v.x = acc[i][0] + r4.x;
            v.y = acc[i][1] + r4.y;
            v.z = acc[i][2] + r4.z;
            v.w = acc[i][3] + r4.w;
            *(float4*)(C + (long)row * ldc + col) = v;
        }
    }
}

// ---------------- causal depthwise conv (K=4) + silu ----------------
// input: cols 0..511 of a 1024-stride buffer; output: 512-stride, optional reversed copy.
__global__ __launch_bounds__(256)
void conv_k(const float* __restrict__ in0, const float* __restrict__ in1,
            const float* __restrict__ cw0, const float* __restrict__ cw1,
            const float* __restrict__ cb0, const float* __restrict__ cb1,
            float* __restrict__ out, long outStrideZ, float* __restrict__ out_rev)
{
    const int dir = blockIdx.z;
    const float* __restrict__ in = dir ? in1 : in0;
    const float* __restrict__ cw = dir ? cw1 : cw0;
    const float* __restrict__ cb = dir ? cb1 : cb0;
    int idx = blockIdx.x * 256 + threadIdx.x;
    if (idx >= T * DI) return;
    int d = idx & (DI - 1);
    int r = idx >> 9;
    int b = r / S, t = r - b * S;
    float acc = cb[d];
#pragma unroll
    for (int k = 0; k < 4; ++k) {
        int tt = t - 3 + k;
        if (tt >= 0) acc = fmaf(cw[d * 4 + k], in[(long)(b * S + tt) * DH + d], acc);
    }
    acc = silu_f(acc);
    (out + (long)dir * outStrideZ)[(long)r * DI + d] = acc;
    if (out_rev) out_rev[(long)(b * S + (S - 1 - t)) * DI + d] = acc;
}

// ---------------- selective scan (both dirs), fused y+u*D and silu(z) gating ----------------
// grid (B, DI/16, 2), 256 threads: thread = (d_local, n); sequential over t.
// Chunked LDS staging (16 steps) with register double-buffered prefetch so the
// next chunk's global loads are in flight during the current chunk's compute.
__global__ __launch_bounds__(256)
void scan_k(const float* __restrict__ delta, const float* __restrict__ dtBC,
            const float* __restrict__ u, const float* __restrict__ xmz,
            const float* __restrict__ Al0, const float* __restrict__ Al1,
            const float* __restrict__ D0, const float* __restrict__ D1,
            float* __restrict__ p)
{
    constexpr int TT  = 16;                 // time-steps per chunk
    constexpr int NC  = (S + TT - 1) / TT;  // 32 chunks
    constexpr int FPC = TT * 20;            // float4 loads per chunk = 320

    __shared__ float dv_s[TT * 16];
    __shared__ float uv_s[TT * 16];
    __shared__ float zv_s[TT * 16];
    __shared__ float bc_s[TT * 32];

    const int dir = blockIdx.z;
    const int b = blockIdx.x;
    const int dblk = blockIdx.y;
    const int tid = threadIdx.x;
    const int n = tid & 15;
    const int dloc = tid >> 4;
    const int d = dblk * 16 + dloc;
    const int d0 = dblk * 16;

    const float* Al = dir ? Al1 : Al0;
    const float A = -expf(Al[d * NST + n]);
    const float Dp = (dir ? D1 : D0)[d];

    const float* dl  = delta + (long)dir * T * DI + (long)b * S * DI;
    const float* bcp = dtBC  + (long)dir * T * 64 + (long)b * S * 64;
    const float* uu  = u     + (long)dir * T * DI + (long)b * S * DI;
    const float* zz  = xmz   + (long)dir * T * DH + (long)b * S * DH + DI;
    float* po        = p     + (long)dir * T * DI + (long)b * S * DI;

    // map flat float4 index i in [0, FPC) -> global source (nullptr if out of range)
    auto gsrc = [&](int i, int c0) -> const float* {
        int t = i / 20, j = i - 20 * (i / 20);
        int ta = c0 + t;
        if (ta >= S) return nullptr;
        if (j < 4)  return dl  + (long)ta * DI + d0 + 4 * j;
        if (j < 8)  return uu  + (long)ta * DI + d0 + 4 * (j - 4);
        if (j < 12) return zz  + (long)ta * DH + d0 + 4 * (j - 8);
        return bcp + (long)ta * 64 + RDT + 4 * (j - 12);
    };
    auto ldst = [&](int i) -> float* {
        int t = i / 20, j = i - 20 * (i / 20);
        if (j < 4)  return dv_s + t * 16 + 4 * j;
        if (j < 8)  return uv_s + t * 16 + 4 * (j - 4);
        if (j < 12) return zv_s + t * 16 + 4 * (j - 8);
        return bc_s + t * 32 + 4 * (j - 12);
    };

    // prologue: load chunk 0 into registers
    float4 r0 = make_float4(0.f, 0.f, 0.f, 0.f);
    float4 r1 = make_float4(0.f, 0.f, 0.f, 0.f);
    {
        const float* s0 = gsrc(tid, 0);
        if (s0) r0 = *(const float4*)s0;
        if (tid + 256 < FPC) {
            const float* s1 = gsrc(tid + 256, 0);
            if (s1) r1 = *(const float4*)s1;
        }
    }

    float h = 0.0f;
    for (int c = 0; c < NC; ++c) {
        const int c0 = c * TT;
        const int tt = min(TT, S - c0);

        // regs -> LDS (implicit vmcnt wait lands here, overlapped with prior compute)
        *(float4*)ldst(tid) = r0;
        if (tid + 256 < FPC) *(float4*)ldst(tid + 256) = r1;
        __syncthreads();

        // issue next chunk's global loads (in flight during compute below)
        if (c + 1 < NC) {
            const float* s0 = gsrc(tid, c0 + TT);
            if (s0) r0 = *(const float4*)s0;
            if (tid + 256 < FPC) {
                const float* s1 = gsrc(tid + 256, c0 + TT);
                if (s1) r1 = *(const float4*)s1;
            }
        }

#define SCAN_STEP(t)                                                        \
        {                                                                   \
            float dv = dv_s[(t) * 16 + dloc];                               \
            float uv = uv_s[(t) * 16 + dloc];                               \
            float Bv = bc_s[(t) * 32 + n];                                  \
            float Cv = bc_s[(t) * 32 + 16 + n];                             \
            float dA = __expf(dv * A);                                      \
            h = fmaf(dA, h, dv * Bv * uv);                                  \
            float yc = h * Cv;                                              \
            yc += __shfl_xor(yc, 1);                                        \
            yc += __shfl_xor(yc, 2);                                        \
            yc += __shfl_xor(yc, 4);                                        \
            yc += __shfl_xor(yc, 8);                                        \
            if (n == 0) {                                                   \
                float zv = zv_s[(t) * 16 + dloc];                           \
                float sz = zv / (1.0f + __expf(-zv));                       \
                po[(long)(c0 + (t)) * DI + d] = (yc + uv * Dp) * sz;        \
            }                                                               \
        }

        if (tt == TT) {
#pragma unroll
            for (int t = 0; t < TT; ++t) SCAN_STEP(t)
        } else {
            for (int t = 0; t < tt; ++t) SCAN_STEP(t)
        }
#undef SCAN_STEP
        __syncthreads();   // protect LDS before next chunk's writes
    }
}

// ---------------- host orchestration ----------------
extern "C" void kernel_launch(void* const* d_in, const int* in_sizes, int n_in,
                              void* d_out, int out_size, void* d_ws, size_t ws_size,
                              hipStream_t stream)
{
    (void)in_sizes; (void)n_in; (void)out_size; (void)ws_size;
    const float* x        = (const float*)d_in[0];
    const float* patch_w  = (const float*)d_in[1];
    const float* patch_b  = (const float*)d_in[2];
    const float* cls_tok  = (const float*)d_in[3];
    const float* ln_g     = (const float*)d_in[4];
    const float* ln_b     = (const float*)d_in[5];
    const float* in_w     = (const float*)d_in[6];
    const float* cw       = (const float*)d_in[7];
    const float* cb       = (const float*)d_in[8];
    const float* out_w    = (const float*)d_in[9];
    const float* fn_g     = (const float*)d_in[10];
    const float* fn_b     = (const float*)d_in[11];
    const float* mf_in    = (const float*)d_in[12];
    const float* mf_cw    = (const float*)d_in[13];
    const float* mf_cb    = (const float*)d_in[14];
    const float* mf_xp    = (const float*)d_in[15];
    const float* mf_dtw   = (const float*)d_in[16];
    const float* mf_dtb   = (const float*)d_in[17];
    const float* mf_Al    = (const float*)d_in[18];
    const float* mf_D     = (const float*)d_in[19];
    const float* mf_ow    = (const float*)d_in[20];
    const float* mb_in    = (const float*)d_in[21];
    const float* mb_cw    = (const float*)d_in[22];
    const float* mb_cb    = (const float*)d_in[23];
    const float* mb_xp    = (const float*)d_in[24];
    const float* mb_dtw   = (const float*)d_in[25];
    const float* mb_dtb   = (const float*)d_in[26];
    const float* mb_Al    = (const float*)d_in[27];
    const float* mb_D     = (const float*)d_in[28];
    const float* mb_ow    = (const float*)d_in[29];

    float* ws = (float*)d_ws;
    float* h      = ws;                    // T*DM
    float* xn     = h     + (long)T * DM;  // T*DM
    float* xcres  = xn    + (long)T * DM;  // T*DH
    float* xc     = xcres + (long)T * DH;  // T*DI
    float* xcrev  = xc    + (long)T * DI;  // T*DI
    float* xmz    = xcrev + (long)T * DI;  // 2*T*DH
    float* u      = xmz   + 2L * T * DH;   // 2*T*DI
    float* dtBC   = u     + 2L * T * DI;   // 2*T*64
    float* delta  = dtBC  + 2L * T * 64;   // 2*T*DI
    float* pbuf   = delta + 2L * T * DI;   // 2*T*DI
    float* ycat   = pbuf  + 2L * T * DI;   // T*DH

    // patch embed + cls
    patch_k<<<dim3(50, B), 256, 0, stream>>>(x, patch_w, patch_b, h);
    cls_k<<<dim3(B), 64, 0, stream>>>(cls_tok, h);

    constexpr int GM = (T + 63) / 64;   // 32

    for (int l = 0; l < LAYERS; ++l) {
        const float* lng = ln_g + (long)l * DM;
        const float* lnb = ln_b + (long)l * DM;
        const float* inw = in_w + (long)l * DH * DM;
        const float* cwl = cw   + (long)l * DI * 4;
        const float* cbl = cb   + (long)l * DI;
        const float* oww = out_w + (long)l * DM * DH;
        const float* fin = mf_in + (long)l * DH * DI;
        const float* bin = mb_in + (long)l * DH * DI;
        const float* fcw = mf_cw + (long)l * DI * 4;
        const float* bcw = mb_cw + (long)l * DI * 4;
        const float* fcb = mf_cb + (long)l * DI;
        const float* bcb = mb_cb + (long)l * DI;
        const float* fxp = mf_xp + (long)l * (RDT + 2 * NST) * DI;
        const float* bxp = mb_xp + (long)l * (RDT + 2 * NST) * DI;
        const float* fdw = mf_dtw + (long)l * DI * RDT;
        const float* bdw = mb_dtw + (long)l * DI * RDT;
        const float* fdb = mf_dtb + (long)l * DI;
        const float* bdb = mb_dtb + (long)l * DI;
        const float* fAl = mf_Al + (long)l * DI * NST;
        const float* bAl = mb_Al + (long)l * DI * NST;
        const float* fD  = mf_D  + (long)l * DI;
        const float* bD  = mb_D  + (long)l * DI;
        const float* fow = mf_ow + (long)l * DI * DI;
        const float* bow = mb_ow + (long)l * DI * DI;

        // xn = LN(h)
        ln_k<<<dim3(T), 64, 0, stream>>>(h, lng, lnb, xn, 1);
        // xcres = xn @ in_w^T  (T x 1024)
        gemm_k<0><<<dim3(GM, DH / 64, 1), 256, 0, stream>>>(
            xn, xn, DM, inw, inw, nullptr, nullptr, xcres, 0, DH, nullptr, T, DH, DM);
        // xc = silu(dwconv(xcres[:, :512])) ; xcrev = time-reversed copy
        conv_k<<<dim3(T * DI / 256, 1, 1), 256, 0, stream>>>(
            xcres, xcres, cwl, cwl, cbl, cbl, xc, 0, xcrev);
        // xmz[dir] = (xc|xcrev) @ m{f,b}_in^T  (T x 1024)
        gemm_k<0><<<dim3(GM, DH / 64, 2), 256, 0, stream>>>(
            xc, xcrev, DI, fin, bin, nullptr, nullptr, xmz, (long)T * DH, DH, nullptr, T, DH, DI);
        // u[dir] = silu(dwconv(xmz[dir][:, :512]))
        conv_k<<<dim3(T * DI / 256, 1, 2), 256, 0, stream>>>(
            xmz, xmz + (long)T * DH, fcw, bcw, fcb, bcb, u, (long)T * DI, nullptr);
        // dtBC[dir] = u[dir] @ xp^T  (T x 64)
        gemm_k<0><<<dim3(GM, 1, 2), 256, 0, stream>>>(
            u, u + (long)T * DI, DI, fxp, bxp, nullptr, nullptr, dtBC, (long)T * 64, 64, nullptr,
            T, 64, DI);
        // delta[dir] = softplus(dt @ dtw^T + dtb)  (T x 512)
        gemm_k<1><<<dim3(GM, DI / 64, 2), 256, 0, stream>>>(
            dtBC, dtBC + (long)T * 64, 64, fdw, bdw, fdb, bdb, delta, (long)T * DI, DI, nullptr,
            T, DI, RDT);
        // p[dir] = (scan(u,delta,A,B,C) + u*D) * silu(z)
        scan_k<<<dim3(B, DI / 16, 2), 256, 0, stream>>>(
            delta, dtBC, u, xmz, fAl, bAl, fD, bD, pbuf);
        // ycat[:, dir*512:...] = (p[dir] @ ow^T) * silu(res), time-flipped back for dir=1
        gemm_k<2><<<dim3(GM, DI / 64, 2), 256, 0, stream>>>(
            pbuf, pbuf + (long)T * DI, DI, fow, bow, nullptr, nullptr, ycat, 0, DH, xcres,
            T, DI, DI);
        // h = ycat @ out_w^T + h
        gemm_k<3><<<dim3(GM, DM / 64, 1), 256, 0, stream>>>(
            ycat, ycat, DH, oww, oww, nullptr, nullptr, h, 0, DM, h, T, DM, DH);
    }

    // final LN on cls rows only -> d_out (4 x 256)
    ln_k<<<dim3(B), 64, 0, stream>>>(h, fn_g, fn_b, (float*)d_out, S);
}

// Round 3
// 2570.155 us; speedup vs baseline: 2.1047x; 1.2824x over previous
//
#include <hip/hip_runtime.h>
#include <math.h>

// ---- static problem dims ----
constexpr int B   = 4;
constexpr int S   = 501;        // 500 patches + cls
constexpr int T   = B * S;      // 2004 token rows
constexpr int DM  = 256;        // d_model
constexpr int DI  = 512;        // mamba inner dim
constexpr int DH  = 1024;       // 2*DI
constexpr int NST = 16;         // d_state
constexpr int RDT = 32;         // dt_rank
constexpr int LAYERS = 8;

// chunked parallel scan params
constexpr int CS     = 16;                    // time-steps per chunk
constexpr int NCH    = (S + CS - 1) / CS;     // 32 chunks
constexpr int NSTATE = 2 * B * DI * NST;      // 65536 scan states (dir,b,d,n)

__device__ __forceinline__ float silu_f(float x) { return x / (1.0f + expf(-x)); }
__device__ __forceinline__ float softplus_f(float x) { return x > 20.0f ? x : log1pf(expf(x)); }

// ---------------- patch embed: strided conv as GEMM with LDS-staged input ----------------
__global__ __launch_bounds__(256)
void patch_k(const float* __restrict__ x, const float* __restrict__ pw,
             const float* __restrict__ pb, float* __restrict__ h)
{
    __shared__ float xs[129 * 100];
    const int tc = blockIdx.x, b = blockIdx.y;
    const int tid = threadIdx.x;
    const int col0 = tc * 100;
    for (int i = tid; i < 129 * 100; i += 256) {
        int c = i / 100, j = i - c * 100;
        xs[i] = x[(long)b * 129 * 5000 + (long)c * 5000 + col0 + j];
    }
    __syncthreads();
    const int o = tid;
    float bias = pb[o];
    float acc[10];
#pragma unroll
    for (int it = 0; it < 10; ++it) acc[it] = bias;
    for (int c = 0; c < 129; ++c) {
#pragma unroll
        for (int k = 0; k < 10; ++k) {
            float w = pw[(long)o * 1290 + c * 10 + k];
#pragma unroll
            for (int it = 0; it < 10; ++it)
                acc[it] = fmaf(w, xs[c * 100 + it * 10 + k], acc[it]);
        }
    }
    long base = ((long)b * S + 1 + tc * 10) * DM;
#pragma unroll
    for (int it = 0; it < 10; ++it)
        h[base + (long)it * DM + o] = acc[it];
}

// grid (B), 64 threads: write cls row
__global__ __launch_bounds__(64)
void cls_k(const float* __restrict__ cls, float* __restrict__ h)
{
    int b = blockIdx.x, lane = threadIdx.x;
    ((float4*)(h + (long)b * S * DM))[lane] = ((const float4*)cls)[lane];
}

// ---------------- layernorm over 256: one wave per row ----------------
__global__ __launch_bounds__(64)
void ln_k(const float* __restrict__ hin, const float* __restrict__ g,
          const float* __restrict__ be, float* __restrict__ out, int rowMul)
{
    long hr = (long)blockIdx.x * rowMul;
    int lane = threadIdx.x;
    float4 v = ((const float4*)(hin + hr * DM))[lane];
    float s = v.x + v.y + v.z + v.w;
    float q = v.x * v.x + v.y * v.y + v.z * v.z + v.w * v.w;
#pragma unroll
    for (int off = 32; off; off >>= 1) { s += __shfl_xor(s, off); q += __shfl_xor(q, off); }
    float mean = s * (1.0f / DM);
    float var  = q * (1.0f / DM) - mean * mean;
    float rs = rsqrtf(var + 1e-5f);
    float4 gg = ((const float4*)g)[lane];
    float4 bb = ((const float4*)be)[lane];
    float4 o;
    o.x = (v.x - mean) * rs * gg.x + bb.x;
    o.y = (v.y - mean) * rs * gg.y + bb.y;
    o.z = (v.z - mean) * rs * gg.z + bb.z;
    o.w = (v.w - mean) * rs * gg.w + bb.w;
    ((float4*)(out + (long)blockIdx.x * DM))[lane] = o;
}

// ---------------- generic fp32 GEMM: C[m,n] = sum_k A[m,k]*W[n,k]  (+ epilogue) ----------------
// EPI: 0=plain store, 1=bias+softplus, 2=gate-cat (mamba out proj), 3=residual add
template<int EPI>
__global__ __launch_bounds__(256)
void gemm_k(const float* __restrict__ A0, const float* __restrict__ A1, int lda,
            const float* __restrict__ W0, const float* __restrict__ W1,
            const float* __restrict__ b0, const float* __restrict__ b1,
            float* __restrict__ Cout, long cStrideZ, int ldc,
            const float* __restrict__ resid,
            int M, int N, int K)
{
    const int dir = blockIdx.z;
    const float* __restrict__ A = dir ? A1 : A0;
    const float* __restrict__ W = dir ? W1 : W0;
    __shared__ float As[16][64];
    __shared__ float Ws[16][64];
    const int tid = threadIdx.x;
    const int tx = tid & 15, ty = tid >> 4;
    const int m0 = blockIdx.x * 64, n0 = blockIdx.y * 64;
    const int arow = tid >> 2;            // 0..63
    const int acol = (tid & 3) * 4;       // 0,4,8,12
    float acc[4][4] = {};

    for (int k0 = 0; k0 < K; k0 += 16) {
        {
            int row = m0 + arow;
            float4 va = make_float4(0.f, 0.f, 0.f, 0.f);
            if (row < M) va = *(const float4*)(A + (long)row * lda + k0 + acol);
            As[acol + 0][arow] = va.x; As[acol + 1][arow] = va.y;
            As[acol + 2][arow] = va.z; As[acol + 3][arow] = va.w;
            float4 vw = *(const float4*)(W + (long)(n0 + arow) * K + k0 + acol);
            Ws[acol + 0][arow] = vw.x; Ws[acol + 1][arow] = vw.y;
            Ws[acol + 2][arow] = vw.z; Ws[acol + 3][arow] = vw.w;
        }
        __syncthreads();
#pragma unroll
        for (int kk = 0; kk < 16; ++kk) {
            float4 av = *(const float4*)&As[kk][ty * 4];
            float4 wv = *(const float4*)&Ws[kk][tx * 4];
            float a[4] = {av.x, av.y, av.z, av.w};
            float w[4] = {wv.x, wv.y, wv.z, wv.w};
#pragma unroll
            for (int i = 0; i < 4; ++i)
#pragma unroll
                for (int j = 0; j < 4; ++j)
                    acc[i][j] = fmaf(a[i], w[j], acc[i][j]);
        }
        __syncthreads();
    }

    const float* bias = dir ? b1 : b0;
    float* C = Cout + (long)dir * cStrideZ;
#pragma unroll
    for (int i = 0; i < 4; ++i) {
        int row = m0 + ty * 4 + i;
        if (row >= M) continue;
        int col = n0 + tx * 4;
        if constexpr (EPI == 0) {
            float4 v = make_float4(acc[i][0], acc[i][1], acc[i][2], acc[i][3]);
            *(float4*)(C + (long)row * ldc + col) = v;
        } else if constexpr (EPI == 1) {
            float4 b4 = *(const float4*)(bias + col);
            float4 v;
            v.x = softplus_f(acc[i][0] + b4.x);
            v.y = softplus_f(acc[i][1] + b4.y);
            v.z = softplus_f(acc[i][2] + b4.z);
            v.w = softplus_f(acc[i][3] + b4.w);
            *(float4*)(C + (long)row * ldc + col) = v;
        } else if constexpr (EPI == 2) {
            int bb = row / S;
            int t  = row - bb * S;
            long rt = dir ? (long)(bb * S + (S - 1 - t)) : (long)row;
            float4 g4 = *(const float4*)(resid + rt * DH + DI + col);
            float4 v;
            v.x = acc[i][0] * silu_f(g4.x);
            v.y = acc[i][1] * silu_f(g4.y);
            v.z = acc[i][2] * silu_f(g4.z);
            v.w = acc[i][3] * silu_f(g4.w);
            *(float4*)(Cout + rt * DH + (dir ? DI : 0) + col) = v;
        } else {   // EPI == 3: residual add
            float4 r4 = *(const float4*)(resid + (long)row * ldc + col);
            float4 v;
            v.x = acc[i][0] + r4.x;
            v.y = acc[i][1] + r4.y;
            v.z = acc[i][2] + r4.z;
            v.w = acc[i][3] + r4.w;
            *(float4*)(C + (long)row * ldc + col) = v;
        }
    }
}

// ---------------- causal depthwise conv (K=4) + silu ----------------
__global__ __launch_bounds__(256)
void conv_k(const float* __restrict__ in0, const float* __restrict__ in1,
            const float* __restrict__ cw0, const float* __restrict__ cw1,
            const float* __restrict__ cb0, const float* __restrict__ cb1,
            float* __restrict__ out, long outStrideZ, float* __restrict__ out_rev)
{
    const int dir = blockIdx.z;
    const float* __restrict__ in = dir ? in1 : in0;
    const float* __restrict__ cw = dir ? cw1 : cw0;
    const float* __restrict__ cb = dir ? cb1 : cb0;
    int idx = blockIdx.x * 256 + threadIdx.x;
    if (idx >= T * DI) return;
    int d = idx & (DI - 1);
    int r = idx >> 9;
    int b = r / S, t = r - b * S;
    float acc = cb[d];
#pragma unroll
    for (int k = 0; k < 4; ++k) {
        int tt = t - 3 + k;
        if (tt >= 0) acc = fmaf(cw[d * 4 + k], in[(long)(b * S + tt) * DH + d], acc);
    }
    acc = silu_f(acc);
    (out + (long)dir * outStrideZ)[(long)r * DI + d] = acc;
    if (out_rev) out_rev[(long)(b * S + (S - 1 - t)) * DI + d] = acc;
}

// ---------------- chunked parallel selective scan ----------------
// Phase A: per chunk, per (d) thread with 16 n-states in registers, compute the
// chunk's affine composition h_end = P*h_start + Q.
// grid (B, NCH, 2dirs), 512 threads (thread = d).
__global__ __launch_bounds__(512)
void scanA_k(const float* __restrict__ delta, const float* __restrict__ dtBC,
             const float* __restrict__ u,
             const float* __restrict__ Al0, const float* __restrict__ Al1,
             float* __restrict__ Pb, float* __restrict__ Qb)
{
    __shared__ float B_s[CS * 16];
    const int b = blockIdx.x, c = blockIdx.y, dir = blockIdx.z;
    const int d = threadIdx.x;
    const int c0 = c * CS;
    const int tt = min(CS, S - c0);

    const float* dl  = delta + (long)dir * T * DI + (long)b * S * DI;
    const float* bcp = dtBC  + (long)dir * T * 64 + (long)b * S * 64;
    const float* uu  = u     + (long)dir * T * DI + (long)b * S * DI;

    if (threadIdx.x < CS * 16) {
        int t = threadIdx.x >> 4, n = threadIdx.x & 15;
        B_s[threadIdx.x] = (t < tt) ? bcp[(long)(c0 + t) * 64 + RDT + n] : 0.f;
    }
    __syncthreads();

    const float* Al = dir ? Al1 : Al0;
    float A2[16], Pv[16], Qv[16];
#pragma unroll
    for (int i = 0; i < 4; ++i) {
        float4 a4 = *(const float4*)(Al + (long)d * NST + 4 * i);
        A2[4 * i + 0] = -__expf(a4.x);
        A2[4 * i + 1] = -__expf(a4.y);
        A2[4 * i + 2] = -__expf(a4.z);
        A2[4 * i + 3] = -__expf(a4.w);
    }
#pragma unroll
    for (int n = 0; n < 16; ++n) { Pv[n] = 1.0f; Qv[n] = 0.0f; }

#pragma unroll 2
    for (int t = 0; t < tt; ++t) {
        float dv = dl[(long)(c0 + t) * DI + d];
        float uv = uu[(long)(c0 + t) * DI + d];
        float dvu = dv * uv;
#pragma unroll
        for (int n = 0; n < 16; ++n) {
            float a = __expf(dv * A2[n]);
            Pv[n] *= a;
            Qv[n] = fmaf(a, Qv[n], dvu * B_s[t * 16 + n]);
        }
    }

    long st0 = ((long)(dir * B + b) * DI + d) * NST;
    long co  = (long)c * NSTATE;
#pragma unroll
    for (int i = 0; i < 4; ++i) {
        *(float4*)(Pb + co + st0 + 4 * i) =
            make_float4(Pv[4 * i], Pv[4 * i + 1], Pv[4 * i + 2], Pv[4 * i + 3]);
        *(float4*)(Qb + co + st0 + 4 * i) =
            make_float4(Qv[4 * i], Qv[4 * i + 1], Qv[4 * i + 2], Qv[4 * i + 3]);
    }
}

// Phase B: prefix over chunks for all states. grid NSTATE/256, 256 threads.
__global__ __launch_bounds__(256)
void scanB_k(const float* __restrict__ Pb, const float* __restrict__ Qb,
             float* __restrict__ h0)
{
    const int st = blockIdx.x * 256 + threadIdx.x;
    float Pv[NCH], Qv[NCH];
#pragma unroll
    for (int c = 0; c < NCH; ++c) {
        Pv[c] = Pb[(long)c * NSTATE + st];
        Qv[c] = Qb[(long)c * NSTATE + st];
    }
    float h = 0.0f;
#pragma unroll
    for (int c = 0; c < NCH; ++c) {
        h0[(long)c * NSTATE + st] = h;
        h = fmaf(Pv[c], h, Qv[c]);
    }
}

// Phase C: replay chunk from h_start; n-states in registers, in-register y reduce,
// fused +u*D and silu(z) gating. grid (B, NCH, 2dirs), 512 threads (thread = d).
__global__ __launch_bounds__(512)
void scanC_k(const float* __restrict__ delta, const float* __restrict__ dtBC,
             const float* __restrict__ u, const float* __restrict__ xmz,
             const float* __restrict__ Al0, const float* __restrict__ Al1,
             const float* __restrict__ D0, const float* __restrict__ D1,
             const float* __restrict__ h0, float* __restrict__ p)
{
    __shared__ float BC_s[CS * 32];
    const int b = blockIdx.x, c = blockIdx.y, dir = blockIdx.z;
    const int d = threadIdx.x;
    const int c0 = c * CS;
    const int tt = min(CS, S - c0);

    const float* dl  = delta + (long)dir * T * DI + (long)b * S * DI;
    const float* bcp = dtBC  + (long)dir * T * 64 + (long)b * S * 64;
    const float* uu  = u     + (long)dir * T * DI + (long)b * S * DI;
    const float* zz  = xmz   + (long)dir * T * DH + (long)b * S * DH + DI;
    float* po        = p     + (long)dir * T * DI + (long)b * S * DI;

    {
        int t = threadIdx.x >> 5, j = threadIdx.x & 31;
        BC_s[threadIdx.x] = (t < tt) ? bcp[(long)(c0 + t) * 64 + RDT + j] : 0.f;
    }
    __syncthreads();

    const float* Al = dir ? Al1 : Al0;
    float A2[16], hv[16];
#pragma unroll
    for (int i = 0; i < 4; ++i) {
        float4 a4 = *(const float4*)(Al + (long)d * NST + 4 * i);
        A2[4 * i + 0] = -__expf(a4.x);
        A2[4 * i + 1] = -__expf(a4.y);
        A2[4 * i + 2] = -__expf(a4.z);
        A2[4 * i + 3] = -__expf(a4.w);
    }
    long st0 = ((long)(dir * B + b) * DI + d) * NST;
#pragma unroll
    for (int i = 0; i < 4; ++i) {
        float4 h4 = *(const float4*)(h0 + (long)c * NSTATE + st0 + 4 * i);
        hv[4 * i + 0] = h4.x; hv[4 * i + 1] = h4.y;
        hv[4 * i + 2] = h4.z; hv[4 * i + 3] = h4.w;
    }
    const float Dp = (dir ? D1 : D0)[d];

#pragma unroll 2
    for (int t = 0; t < tt; ++t) {
        float dv = dl[(long)(c0 + t) * DI + d];
        float uv = uu[(long)(c0 + t) * DI + d];
        float zv = zz[(long)(c0 + t) * DH + d];
        float dvu = dv * uv;
        float y = 0.0f;
#pragma unroll
        for (int n = 0; n < 16; ++n) {
            float a = __expf(dv * A2[n]);
            hv[n] = fmaf(a, hv[n], dvu * BC_s[t * 32 + n]);
            y = fmaf(hv[n], BC_s[t * 32 + 16 + n], y);
        }
        float sz = zv / (1.0f + __expf(-zv));
        po[(long)(c0 + t) * DI + d] = (y + uv * Dp) * sz;
    }
}

// ---------------- host orchestration ----------------
extern "C" void kernel_launch(void* const* d_in, const int* in_sizes, int n_in,
                              void* d_out, int out_size, void* d_ws, size_t ws_size,
                              hipStream_t stream)
{
    (void)in_sizes; (void)n_in; (void)out_size; (void)ws_size;
    const float* x        = (const float*)d_in[0];
    const float* patch_w  = (const float*)d_in[1];
    const float* patch_b  = (const float*)d_in[2];
    const float* cls_tok  = (const float*)d_in[3];
    const float* ln_g     = (const float*)d_in[4];
    const float* ln_b     = (const float*)d_in[5];
    const float* in_w     = (const float*)d_in[6];
    const float* cw       = (const float*)d_in[7];
    const float* cb       = (const float*)d_in[8];
    const float* out_w    = (const float*)d_in[9];
    const float* fn_g     = (const float*)d_in[10];
    const float* fn_b     = (const float*)d_in[11];
    const float* mf_in    = (const float*)d_in[12];
    const float* mf_cw    = (const float*)d_in[13];
    const float* mf_cb    = (const float*)d_in[14];
    const float* mf_xp    = (const float*)d_in[15];
    const float* mf_dtw   = (const float*)d_in[16];
    const float* mf_dtb   = (const float*)d_in[17];
    const float* mf_Al    = (const float*)d_in[18];
    const float* mf_D     = (const float*)d_in[19];
    const float* mf_ow    = (const float*)d_in[20];
    const float* mb_in    = (const float*)d_in[21];
    const float* mb_cw    = (const float*)d_in[22];
    const float* mb_cb    = (const float*)d_in[23];
    const float* mb_xp    = (const float*)d_in[24];
    const float* mb_dtw   = (const float*)d_in[25];
    const float* mb_dtb   = (const float*)d_in[26];
    const float* mb_Al    = (const float*)d_in[27];
    const float* mb_D     = (const float*)d_in[28];
    const float* mb_ow    = (const float*)d_in[29];

    float* ws = (float*)d_ws;
    float* h      = ws;                    // T*DM
    float* xn     = h     + (long)T * DM;  // T*DM
    float* xcres  = xn    + (long)T * DM;  // T*DH
    float* xc     = xcres + (long)T * DH;  // T*DI
    float* xcrev  = xc    + (long)T * DI;  // T*DI
    float* xmz    = xcrev + (long)T * DI;  // 2*T*DH
    float* u      = xmz   + 2L * T * DH;   // 2*T*DI
    float* dtBC   = u     + 2L * T * DI;   // 2*T*64
    float* delta  = dtBC  + 2L * T * 64;   // 2*T*DI
    float* pbuf   = delta + 2L * T * DI;   // 2*T*DI
    float* ycat   = pbuf  + 2L * T * DI;   // T*DH
    float* Pb     = ycat  + (long)T * DH;  // NCH*NSTATE
    float* Qb     = Pb    + (long)NCH * NSTATE;
    float* h0b    = Qb    + (long)NCH * NSTATE;

    // patch embed + cls
    patch_k<<<dim3(50, B), 256, 0, stream>>>(x, patch_w, patch_b, h);
    cls_k<<<dim3(B), 64, 0, stream>>>(cls_tok, h);

    constexpr int GM = (T + 63) / 64;   // 32

    for (int l = 0; l < LAYERS; ++l) {
        const float* lng = ln_g + (long)l * DM;
        const float* lnb = ln_b + (long)l * DM;
        const float* inw = in_w + (long)l * DH * DM;
        const float* cwl = cw   + (long)l * DI * 4;
        const float* cbl = cb   + (long)l * DI;
        const float* oww = out_w + (long)l * DM * DH;
        const float* fin = mf_in + (long)l * DH * DI;
        const float* bin = mb_in + (long)l * DH * DI;
        const float* fcw = mf_cw + (long)l * DI * 4;
        const float* bcw = mb_cw + (long)l * DI * 4;
        const float* fcb = mf_cb + (long)l * DI;
        const float* bcb = mb_cb + (long)l * DI;
        const float* fxp = mf_xp + (long)l * (RDT + 2 * NST) * DI;
        const float* bxp = mb_xp + (long)l * (RDT + 2 * NST) * DI;
        const float* fdw = mf_dtw + (long)l * DI * RDT;
        const float* bdw = mb_dtw + (long)l * DI * RDT;
        const float* fdb = mf_dtb + (long)l * DI;
        const float* bdb = mb_dtb + (long)l * DI;
        const float* fAl = mf_Al + (long)l * DI * NST;
        const float* bAl = mb_Al + (long)l * DI * NST;
        const float* fD  = mf_D  + (long)l * DI;
        const float* bD  = mb_D  + (long)l * DI;
        const float* fow = mf_ow + (long)l * DI * DI;
        const float* bow = mb_ow + (long)l * DI * DI;

        // xn = LN(h)
        ln_k<<<dim3(T), 64, 0, stream>>>(h, lng, lnb, xn, 1);
        // xcres = xn @ in_w^T  (T x 1024)
        gemm_k<0><<<dim3(GM, DH / 64, 1), 256, 0, stream>>>(
            xn, xn, DM, inw, inw, nullptr, nullptr, xcres, 0, DH, nullptr, T, DH, DM);
        // xc = silu(dwconv(xcres[:, :512])) ; xcrev = time-reversed copy
        conv_k<<<dim3(T * DI / 256, 1, 1), 256, 0, stream>>>(
            xcres, xcres, cwl, cwl, cbl, cbl, xc, 0, xcrev);
        // xmz[dir] = (xc|xcrev) @ m{f,b}_in^T  (T x 1024)
        gemm_k<0><<<dim3(GM, DH / 64, 2), 256, 0, stream>>>(
            xc, xcrev, DI, fin, bin, nullptr, nullptr, xmz, (long)T * DH, DH, nullptr, T, DH, DI);
        // u[dir] = silu(dwconv(xmz[dir][:, :512]))
        conv_k<<<dim3(T * DI / 256, 1, 2), 256, 0, stream>>>(
            xmz, xmz + (long)T * DH, fcw, bcw, fcb, bcb, u, (long)T * DI, nullptr);
        // dtBC[dir] = u[dir] @ xp^T  (T x 64)
        gemm_k<0><<<dim3(GM, 1, 2), 256, 0, stream>>>(
            u, u + (long)T * DI, DI, fxp, bxp, nullptr, nullptr, dtBC, (long)T * 64, 64, nullptr,
            T, 64, DI);
        // delta[dir] = softplus(dt @ dtw^T + dtb)  (T x 512)
        gemm_k<1><<<dim3(GM, DI / 64, 2), 256, 0, stream>>>(
            dtBC, dtBC + (long)T * 64, 64, fdw, bdw, fdb, bdb, delta, (long)T * DI, DI, nullptr,
            T, DI, RDT);
        // chunked parallel scan: A (per-chunk P,Q) -> B (chunk prefix) -> C (replay + gate)
        scanA_k<<<dim3(B, NCH, 2), 512, 0, stream>>>(delta, dtBC, u, fAl, bAl, Pb, Qb);
        scanB_k<<<dim3(NSTATE / 256), 256, 0, stream>>>(Pb, Qb, h0b);
        scanC_k<<<dim3(B, NCH, 2), 512, 0, stream>>>(
            delta, dtBC, u, xmz, fAl, bAl, fD, bD, h0b, pbuf);
        // ycat[:, dir*512:...] = (p[dir] @ ow^T) * silu(res), time-flipped back for dir=1
        gemm_k<2><<<dim3(GM, DI / 64, 2), 256, 0, stream>>>(
            pbuf, pbuf + (long)T * DI, DI, fow, bow, nullptr, nullptr, ycat, 0, DH, xcres,
            T, DI, DI);
        // h = ycat @ out_w^T + h
        gemm_k<3><<<dim3(GM, DM / 64, 1), 256, 0, stream>>>(
            ycat, ycat, DH, oww, oww, nullptr, nullptr, h, 0, DM, h, T, DM, DH);
    }

    // final LN on cls rows only -> d_out (4 x 256)
    ln_k<<<dim3(B), 64, 0, stream>>>(h, fn_g, fn_b, (float*)d_out, S);
}

// Round 4
// 2383.346 us; speedup vs baseline: 2.2697x; 1.0784x over previous
//
#include <hip/hip_runtime.h>
#include <math.h>

// ---- static problem dims ----
constexpr int B   = 4;
constexpr int S   = 501;        // 500 patches + cls
constexpr int T   = B * S;      // 2004 token rows
constexpr int DM  = 256;        // d_model
constexpr int DI  = 512;        // mamba inner dim
constexpr int DH  = 1024;       // 2*DI
constexpr int NST = 16;         // d_state
constexpr int RDT = 32;         // dt_rank
constexpr int LAYERS = 8;

// chunked parallel scan params
constexpr int CS     = 16;                    // time-steps per chunk
constexpr int NCH    = (S + CS - 1) / CS;     // 32 chunks
constexpr int NSTATE = 2 * B * DI * NST;      // 65536 scan states (dir,b,d,n)

typedef __attribute__((ext_vector_type(8))) short bf16x8;
typedef __attribute__((ext_vector_type(4))) float f32x4;

__device__ __forceinline__ float silu_f(float x) { return x / (1.0f + expf(-x)); }
__device__ __forceinline__ float softplus_f(float x) { return x > 20.0f ? x : log1pf(expf(x)); }

__device__ __forceinline__ unsigned short f2bf(float f) {
    unsigned u = __float_as_uint(f);
    u += 0x7FFF + ((u >> 16) & 1);          // round-to-nearest-even
    return (unsigned short)(u >> 16);
}
__device__ __forceinline__ float bf2f(unsigned short s) {
    return __uint_as_float((unsigned)s << 16);
}

// ---------------- patch embed ----------------
__global__ __launch_bounds__(256)
void patch_k(const float* __restrict__ x, const float* __restrict__ pw,
             const float* __restrict__ pb, float* __restrict__ h)
{
    __shared__ float xs[129 * 100];
    const int tc = blockIdx.x, b = blockIdx.y;
    const int tid = threadIdx.x;
    const int col0 = tc * 100;
    for (int i = tid; i < 129 * 100; i += 256) {
        int c = i / 100, j = i - c * 100;
        xs[i] = x[(long)b * 129 * 5000 + (long)c * 5000 + col0 + j];
    }
    __syncthreads();
    const int o = tid;
    float bias = pb[o];
    float acc[10];
#pragma unroll
    for (int it = 0; it < 10; ++it) acc[it] = bias;
#pragma unroll 3
    for (int c = 0; c < 129; ++c) {
        float wv[10];
#pragma unroll
        for (int q = 0; q < 5; ++q) {
            float2 w2 = *(const float2*)(pw + (long)o * 1290 + c * 10 + 2 * q);
            wv[2 * q] = w2.x; wv[2 * q + 1] = w2.y;
        }
#pragma unroll
        for (int k = 0; k < 10; ++k) {
#pragma unroll
            for (int it = 0; it < 10; ++it)
                acc[it] = fmaf(wv[k], xs[c * 100 + it * 10 + k], acc[it]);
        }
    }
    long base = ((long)b * S + 1 + tc * 10) * DM;
#pragma unroll
    for (int it = 0; it < 10; ++it)
        h[base + (long)it * DM + o] = acc[it];
}

// grid (B), 64 threads: write cls row
__global__ __launch_bounds__(64)
void cls_k(const float* __restrict__ cls, float* __restrict__ h)
{
    int b = blockIdx.x, lane = threadIdx.x;
    ((float4*)(h + (long)b * S * DM))[lane] = ((const float4*)cls)[lane];
}

// ---------------- layernorm over 256: one wave per row ----------------
__global__ __launch_bounds__(64)
void ln_k(const float* __restrict__ hin, const float* __restrict__ g,
          const float* __restrict__ be, float* __restrict__ out, int rowMul)
{
    long hr = (long)blockIdx.x * rowMul;
    int lane = threadIdx.x;
    float4 v = ((const float4*)(hin + hr * DM))[lane];
    float s = v.x + v.y + v.z + v.w;
    float q = v.x * v.x + v.y * v.y + v.z * v.z + v.w * v.w;
#pragma unroll
    for (int off = 32; off; off >>= 1) { s += __shfl_xor(s, off); q += __shfl_xor(q, off); }
    float mean = s * (1.0f / DM);
    float var  = q * (1.0f / DM) - mean * mean;
    float rs = rsqrtf(var + 1e-5f);
    float4 gg = ((const float4*)g)[lane];
    float4 bb = ((const float4*)be)[lane];
    float4 o;
    o.x = (v.x - mean) * rs * gg.x + bb.x;
    o.y = (v.y - mean) * rs * gg.y + bb.y;
    o.z = (v.z - mean) * rs * gg.z + bb.z;
    o.w = (v.w - mean) * rs * gg.w + bb.w;
    ((float4*)(out + (long)blockIdx.x * DM))[lane] = o;
}

// ---------------- bf16x3 MFMA GEMM: C[m,n] = sum_k A[m,k]*W[n,k] (+ epilogue) ----------------
// fp32 inputs split into hi/lo bf16 in LDS; 3 MFMA terms (hh, hl, lh) reproduce fp32
// to ~1e-5 rel.  Tile BMxBN, BK=32, 256 threads = 4 waves (2x2), 16x16x32 MFMA frags.
// LDS rows padded to 40 bf16 (80B) -> frag ds_read_b128 spreads over all 32 banks.
// EPI: 0=plain store, 2=gate-cat (mamba out proj), 3=residual add
template<int BM, int BN, int EPI>
__global__ __launch_bounds__(256, 2)
void mgemm_k(const float* __restrict__ A0, const float* __restrict__ A1, int lda,
             const float* __restrict__ W0, const float* __restrict__ W1,
             float* __restrict__ Cout, long cStrideZ, int ldc,
             const float* __restrict__ resid,
             int M, int N, int K)
{
    constexpr int MI = BM / 2 / 16;     // frags per wave in m (4 for 128, 2 for 64)
    constexpr int NJ = BN / 2 / 16;
    constexpr int LDAs = 40;            // padded LDS row (shorts)

    __shared__ short sm[(2 * BM + 2 * BN) * LDAs];
    short* Ah = sm;
    short* Alo = sm + BM * LDAs;
    short* Wh = sm + 2 * BM * LDAs;
    short* Wlo = sm + 2 * BM * LDAs + BN * LDAs;

    const int dir = blockIdx.z;
    const float* __restrict__ A = dir ? A1 : A0;
    const float* __restrict__ W = dir ? W1 : W0;
    const int tid = threadIdx.x;
    const int lane = tid & 63;
    const int wave = tid >> 6;
    const int wr = wave >> 1, wc = wave & 1;
    const int m0 = blockIdx.x * BM, n0 = blockIdx.y * BN;
    const int kl = lane >> 4;          // 0..3 k-group
    const int rl = lane & 15;          // row within frag

    f32x4 acc[MI][NJ];
#pragma unroll
    for (int i = 0; i < MI; ++i)
#pragma unroll
        for (int j = 0; j < NJ; ++j)
            acc[i][j] = (f32x4){0.f, 0.f, 0.f, 0.f};

    auto split8 = [](const float* xs, short* hdst, short* ldst) {
        short hh[8], ll[8];
#pragma unroll
        for (int e = 0; e < 8; ++e) {
            unsigned short hb = f2bf(xs[e]);
            hh[e] = (short)hb;
            ll[e] = (short)f2bf(xs[e] - bf2f(hb));
        }
        *(bf16x8*)hdst = *(const bf16x8*)hh;
        *(bf16x8*)ldst = *(const bf16x8*)ll;
    };

    for (int k0 = 0; k0 < K; k0 += 32) {
        // ---- stage A and W tiles (fp32 -> hi/lo bf16) ----
        if constexpr (BM == 128) {
            // all 256 threads stage A (128x32) and W (128x32)
            {
                int row = tid >> 1, cs = (tid & 1) * 16;
                bool ok = (m0 + row) < M;
                float v[16];
#pragma unroll
                for (int j = 0; j < 4; ++j) {
                    float4 t4 = ok ? *(const float4*)(A + (long)(m0 + row) * lda + k0 + cs + 4 * j)
                                   : make_float4(0.f, 0.f, 0.f, 0.f);
                    v[4 * j] = t4.x; v[4 * j + 1] = t4.y; v[4 * j + 2] = t4.z; v[4 * j + 3] = t4.w;
                }
                split8(v,     Ah  + row * LDAs + cs,     Alo + row * LDAs + cs);
                split8(v + 8, Ah  + row * LDAs + cs + 8, Alo + row * LDAs + cs + 8);
            }
            {
                int row = tid >> 1, cs = (tid & 1) * 16;
                float v[16];
#pragma unroll
                for (int j = 0; j < 4; ++j) {
                    float4 t4 = *(const float4*)(W + (long)(n0 + row) * K + k0 + cs + 4 * j);
                    v[4 * j] = t4.x; v[4 * j + 1] = t4.y; v[4 * j + 2] = t4.z; v[4 * j + 3] = t4.w;
                }
                split8(v,     Wh  + row * LDAs + cs,     Wlo + row * LDAs + cs);
                split8(v + 8, Wh  + row * LDAs + cs + 8, Wlo + row * LDAs + cs + 8);
            }
        } else {
            // BM==BN==64: threads 0..127 stage A, 128..255 stage W
            int t2 = tid & 127;
            int row = t2 >> 1, cs = (t2 & 1) * 16;
            float v[16];
            if (tid < 128) {
                bool ok = (m0 + row) < M;
#pragma unroll
                for (int j = 0; j < 4; ++j) {
                    float4 t4 = ok ? *(const float4*)(A + (long)(m0 + row) * lda + k0 + cs + 4 * j)
                                   : make_float4(0.f, 0.f, 0.f, 0.f);
                    v[4 * j] = t4.x; v[4 * j + 1] = t4.y; v[4 * j + 2] = t4.z; v[4 * j + 3] = t4.w;
                }
                split8(v,     Ah  + row * LDAs + cs,     Alo + row * LDAs + cs);
                split8(v + 8, Ah  + row * LDAs + cs + 8, Alo + row * LDAs + cs + 8);
            } else {
#pragma unroll
                for (int j = 0; j < 4; ++j) {
                    float4 t4 = *(const float4*)(W + (long)(n0 + row) * K + k0 + cs + 4 * j);
                    v[4 * j] = t4.x; v[4 * j + 1] = t4.y; v[4 * j + 2] = t4.z; v[4 * j + 3] = t4.w;
                }
                split8(v,     Wh  + row * LDAs + cs,     Wlo + row * LDAs + cs);
                split8(v + 8, Wh  + row * LDAs + cs + 8, Wlo + row * LDAs + cs + 8);
            }
        }
        __syncthreads();

        // ---- frag loads + 3-term MFMA ----
        bf16x8 ah[MI], al[MI], wh[NJ], wl[NJ];
#pragma unroll
        for (int i = 0; i < MI; ++i) {
            int r = wr * (BM / 2) + i * 16 + rl;
            ah[i] = *(const bf16x8*)&Ah [r * LDAs + kl * 8];
            al[i] = *(const bf16x8*)&Alo[r * LDAs + kl * 8];
        }
#pragma unroll
        for (int j = 0; j < NJ; ++j) {
            int r = wc * (BN / 2) + j * 16 + rl;
            wh[j] = *(const bf16x8*)&Wh [r * LDAs + kl * 8];
            wl[j] = *(const bf16x8*)&Wlo[r * LDAs + kl * 8];
        }
#pragma unroll
        for (int i = 0; i < MI; ++i)
#pragma unroll
            for (int j = 0; j < NJ; ++j) {
                acc[i][j] = __builtin_amdgcn_mfma_f32_16x16x32_bf16(ah[i], wl[j], acc[i][j], 0, 0, 0);
                acc[i][j] = __builtin_amdgcn_mfma_f32_16x16x32_bf16(al[i], wh[j], acc[i][j], 0, 0, 0);
                acc[i][j] = __builtin_amdgcn_mfma_f32_16x16x32_bf16(ah[i], wh[j], acc[i][j], 0, 0, 0);
            }
        __syncthreads();
    }

    // ---- epilogue: D layout col=lane&15, row=(lane>>4)*4+r ----
    float* C = Cout + (long)dir * cStrideZ;
#pragma unroll
    for (int i = 0; i < MI; ++i) {
#pragma unroll
        for (int j = 0; j < NJ; ++j) {
            int rbase = m0 + wr * (BM / 2) + i * 16 + (lane >> 4) * 4;
            int colg = n0 + wc * (BN / 2) + j * 16 + (lane & 15);
#pragma unroll
            for (int r = 0; r < 4; ++r) {
                int rowg = rbase + r;
                if (rowg >= M) continue;
                float val = acc[i][j][r];
                if constexpr (EPI == 0) {
                    C[(long)rowg * ldc + colg] = val;
                } else if constexpr (EPI == 2) {
                    int bb = rowg / S;
                    int t  = rowg - bb * S;
                    long rt = dir ? (long)(bb * S + (S - 1 - t)) : (long)rowg;
                    float g = resid[rt * DH + DI + colg];
                    Cout[rt * DH + (dir ? DI : 0) + colg] = val * silu_f(g);
                } else {   // EPI == 3
                    C[(long)rowg * ldc + colg] = val + resid[(long)rowg * ldc + colg];
                }
            }
        }
    }
}

// ---------------- fp32 GEMM for small shapes (xp N=64, dtw K=32) ----------------
// EPI: 0=plain store, 1=bias+softplus
template<int EPI>
__global__ __launch_bounds__(256)
void gemm_k(const float* __restrict__ A0, const float* __restrict__ A1, int lda,
            const float* __restrict__ W0, const float* __restrict__ W1,
            const float* __restrict__ b0, const float* __restrict__ b1,
            float* __restrict__ Cout, long cStrideZ, int ldc,
            int M, int N, int K)
{
    const int dir = blockIdx.z;
    const float* __restrict__ A = dir ? A1 : A0;
    const float* __restrict__ W = dir ? W1 : W0;
    __shared__ float As[16][64];
    __shared__ float Ws[16][64];
    const int tid = threadIdx.x;
    const int tx = tid & 15, ty = tid >> 4;
    const int m0 = blockIdx.x * 64, n0 = blockIdx.y * 64;
    const int arow = tid >> 2;
    const int acol = (tid & 3) * 4;
    float acc[4][4] = {};

    for (int k0 = 0; k0 < K; k0 += 16) {
        {
            int row = m0 + arow;
            float4 va = make_float4(0.f, 0.f, 0.f, 0.f);
            if (row < M) va = *(const float4*)(A + (long)row * lda + k0 + acol);
            As[acol + 0][arow] = va.x; As[acol + 1][arow] = va.y;
            As[acol + 2][arow] = va.z; As[acol + 3][arow] = va.w;
            float4 vw = *(const float4*)(W + (long)(n0 + arow) * K + k0 + acol);
            Ws[acol + 0][arow] = vw.x; Ws[acol + 1][arow] = vw.y;
            Ws[acol + 2][arow] = vw.z; Ws[acol + 3][arow] = vw.w;
        }
        __syncthreads();
#pragma unroll
        for (int kk = 0; kk < 16; ++kk) {
            float4 av = *(const float4*)&As[kk][ty * 4];
            float4 wv = *(const float4*)&Ws[kk][tx * 4];
            float a[4] = {av.x, av.y, av.z, av.w};
            float w[4] = {wv.x, wv.y, wv.z, wv.w};
#pragma unroll
            for (int i = 0; i < 4; ++i)
#pragma unroll
                for (int j = 0; j < 4; ++j)
                    acc[i][j] = fmaf(a[i], w[j], acc[i][j]);
        }
        __syncthreads();
    }

    const float* bias = dir ? b1 : b0;
    float* C = Cout + (long)dir * cStrideZ;
#pragma unroll
    for (int i = 0; i < 4; ++i) {
        int row = m0 + ty * 4 + i;
        if (row >= M) continue;
        int col = n0 + tx * 4;
        if constexpr (EPI == 0) {
            float4 v = make_float4(acc[i][0], acc[i][1], acc[i][2], acc[i][3]);
            *(float4*)(C + (long)row * ldc + col) = v;
        } else {
            float4 b4 = *(const float4*)(bias + col);
            float4 v;
            v.x = softplus_f(acc[i][0] + b4.x);
            v.y = softplus_f(acc[i][1] + b4.y);
            v.z = softplus_f(acc[i][2] + b4.z);
            v.w = softplus_f(acc[i][3] + b4.w);
            *(float4*)(C + (long)row * ldc + col) = v;
        }
    }
}

// ---------------- causal depthwise conv (K=4) + silu ----------------
__global__ __launch_bounds__(256)
void conv_k(const float* __restrict__ in0, const float* __restrict__ in1,
            const float* __restrict__ cw0, const float* __restrict__ cw1,
            const float* __restrict__ cb0, const float* __restrict__ cb1,
            float* __restrict__ out, long outStrideZ, float* __restrict__ out_rev)
{
    const int dir = blockIdx.z;
    const float* __restrict__ in = dir ? in1 : in0;
    const float* __restrict__ cw = dir ? cw1 : cw0;
    const float* __restrict__ cb = dir ? cb1 : cb0;
    int idx = blockIdx.x * 256 + threadIdx.x;
    if (idx >= T * DI) return;
    int d = idx & (DI - 1);
    int r = idx >> 9;
    int b = r / S, t = r - b * S;
    float acc = cb[d];
#pragma unroll
    for (int k = 0; k < 4; ++k) {
        int tt = t - 3 + k;
        if (tt >= 0) acc = fmaf(cw[d * 4 + k], in[(long)(b * S + tt) * DH + d], acc);
    }
    acc = silu_f(acc);
    (out + (long)dir * outStrideZ)[(long)r * DI + d] = acc;
    if (out_rev) out_rev[(long)(b * S + (S - 1 - t)) * DI + d] = acc;
}

// ---------------- chunked parallel selective scan ----------------
__global__ __launch_bounds__(512)
void scanA_k(const float* __restrict__ delta, const float* __restrict__ dtBC,
             const float* __restrict__ u,
             const float* __restrict__ Al0, const float* __restrict__ Al1,
             float* __restrict__ Pb, float* __restrict__ Qb)
{
    __shared__ float B_s[CS * 16];
    const int b = blockIdx.x, c = blockIdx.y, dir = blockIdx.z;
    const int d = threadIdx.x;
    const int c0 = c * CS;
    const int tt = min(CS, S - c0);

    const float* dl  = delta + (long)dir * T * DI + (long)b * S * DI;
    const float* bcp = dtBC  + (long)dir * T * 64 + (long)b * S * 64;
    const float* uu  = u     + (long)dir * T * DI + (long)b * S * DI;

    if (threadIdx.x < CS * 16) {
        int t = threadIdx.x >> 4, n = threadIdx.x & 15;
        B_s[threadIdx.x] = (t < tt) ? bcp[(long)(c0 + t) * 64 + RDT + n] : 0.f;
    }
    __syncthreads();

    const float* Al = dir ? Al1 : Al0;
    float A2[16], Pv[16], Qv[16];
#pragma unroll
    for (int i = 0; i < 4; ++i) {
        float4 a4 = *(const float4*)(Al + (long)d * NST + 4 * i);
        A2[4 * i + 0] = -__expf(a4.x);
        A2[4 * i + 1] = -__expf(a4.y);
        A2[4 * i + 2] = -__expf(a4.z);
        A2[4 * i + 3] = -__expf(a4.w);
    }
#pragma unroll
    for (int n = 0; n < 16; ++n) { Pv[n] = 1.0f; Qv[n] = 0.0f; }

#pragma unroll 2
    for (int t = 0; t < tt; ++t) {
        float dv = dl[(long)(c0 + t) * DI + d];
        float uv = uu[(long)(c0 + t) * DI + d];
        float dvu = dv * uv;
#pragma unroll
        for (int n = 0; n < 16; ++n) {
            float a = __expf(dv * A2[n]);
            Pv[n] *= a;
            Qv[n] = fmaf(a, Qv[n], dvu * B_s[t * 16 + n]);
        }
    }

    long st0 = ((long)(dir * B + b) * DI + d) * NST;
    long co  = (long)c * NSTATE;
#pragma unroll
    for (int i = 0; i < 4; ++i) {
        *(float4*)(Pb + co + st0 + 4 * i) =
            make_float4(Pv[4 * i], Pv[4 * i + 1], Pv[4 * i + 2], Pv[4 * i + 3]);
        *(float4*)(Qb + co + st0 + 4 * i) =
            make_float4(Qv[4 * i], Qv[4 * i + 1], Qv[4 * i + 2], Qv[4 * i + 3]);
    }
}

__global__ __launch_bounds__(256)
void scanB_k(const float* __restrict__ Pb, const float* __restrict__ Qb,
             float* __restrict__ h0)
{
    const int st = blockIdx.x * 256 + threadIdx.x;
    float Pv[NCH], Qv[NCH];
#pragma unroll
    for (int c = 0; c < NCH; ++c) {
        Pv[c] = Pb[(long)c * NSTATE + st];
        Qv[c] = Qb[(long)c * NSTATE + st];
    }
    float h = 0.0f;
#pragma unroll
    for (int c = 0; c < NCH; ++c) {
        h0[(long)c * NSTATE + st] = h;
        h = fmaf(Pv[c], h, Qv[c]);
    }
}

__global__ __launch_bounds__(512)
void scanC_k(const float* __restrict__ delta, const float* __restrict__ dtBC,
             const float* __restrict__ u, const float* __restrict__ xmz,
             const float* __restrict__ Al0, const float* __restrict__ Al1,
             const float* __restrict__ D0, const float* __restrict__ D1,
             const float* __restrict__ h0, float* __restrict__ p)
{
    __shared__ float BC_s[CS * 32];
    const int b = blockIdx.x, c = blockIdx.y, dir = blockIdx.z;
    const int d = threadIdx.x;
    const int c0 = c * CS;
    const int tt = min(CS, S - c0);

    const float* dl  = delta + (long)dir * T * DI + (long)b * S * DI;
    const float* bcp = dtBC  + (long)dir * T * 64 + (long)b * S * 64;
    const float* uu  = u     + (long)dir * T * DI + (long)b * S * DI;
    const float* zz  = xmz   + (long)dir * T * DH + (long)b * S * DH + DI;
    float* po        = p     + (long)dir * T * DI + (long)b * S * DI;

    {
        int t = threadIdx.x >> 5, j = threadIdx.x & 31;
        BC_s[threadIdx.x] = (t < tt) ? bcp[(long)(c0 + t) * 64 + RDT + j] : 0.f;
    }
    __syncthreads();

    const float* Al = dir ? Al1 : Al0;
    float A2[16], hv[16];
#pragma unroll
    for (int i = 0; i < 4; ++i) {
        float4 a4 = *(const float4*)(Al + (long)d * NST + 4 * i);
        A2[4 * i + 0] = -__expf(a4.x);
        A2[4 * i + 1] = -__expf(a4.y);
        A2[4 * i + 2] = -__expf(a4.z);
        A2[4 * i + 3] = -__expf(a4.w);
    }
    long st0 = ((long)(dir * B + b) * DI + d) * NST;
#pragma unroll
    for (int i = 0; i < 4; ++i) {
        float4 h4 = *(const float4*)(h0 + (long)c * NSTATE + st0 + 4 * i);
        hv[4 * i + 0] = h4.x; hv[4 * i + 1] = h4.y;
        hv[4 * i + 2] = h4.z; hv[4 * i + 3] = h4.w;
    }
    const float Dp = (dir ? D1 : D0)[d];

#pragma unroll 2
    for (int t = 0; t < tt; ++t) {
        float dv = dl[(long)(c0 + t) * DI + d];
        float uv = uu[(long)(c0 + t) * DI + d];
        float zv = zz[(long)(c0 + t) * DH + d];
        float dvu = dv * uv;
        float y = 0.0f;
#pragma unroll
        for (int n = 0; n < 16; ++n) {
            float a = __expf(dv * A2[n]);
            hv[n] = fmaf(a, hv[n], dvu * BC_s[t * 32 + n]);
            y = fmaf(hv[n], BC_s[t * 32 + 16 + n], y);
        }
        float sz = zv / (1.0f + __expf(-zv));
        po[(long)(c0 + t) * DI + d] = (y + uv * Dp) * sz;
    }
}

// ---------------- host orchestration ----------------
extern "C" void kernel_launch(void* const* d_in, const int* in_sizes, int n_in,
                              void* d_out, int out_size, void* d_ws, size_t ws_size,
                              hipStream_t stream)
{
    (void)in_sizes; (void)n_in; (void)out_size; (void)ws_size;
    const float* x        = (const float*)d_in[0];
    const float* patch_w  = (const float*)d_in[1];
    const float* patch_b  = (const float*)d_in[2];
    const float* cls_tok  = (const float*)d_in[3];
    const float* ln_g     = (const float*)d_in[4];
    const float* ln_b     = (const float*)d_in[5];
    const float* in_w     = (const float*)d_in[6];
    const float* cw       = (const float*)d_in[7];
    const float* cb       = (const float*)d_in[8];
    const float* out_w    = (const float*)d_in[9];
    const float* fn_g     = (const float*)d_in[10];
    const float* fn_b     = (const float*)d_in[11];
    const float* mf_in    = (const float*)d_in[12];
    const float* mf_cw    = (const float*)d_in[13];
    const float* mf_cb    = (const float*)d_in[14];
    const float* mf_xp    = (const float*)d_in[15];
    const float* mf_dtw   = (const float*)d_in[16];
    const float* mf_dtb   = (const float*)d_in[17];
    const float* mf_Al    = (const float*)d_in[18];
    const float* mf_D     = (const float*)d_in[19];
    const float* mf_ow    = (const float*)d_in[20];
    const float* mb_in    = (const float*)d_in[21];
    const float* mb_cw    = (const float*)d_in[22];
    const float* mb_cb    = (const float*)d_in[23];
    const float* mb_xp    = (const float*)d_in[24];
    const float* mb_dtw   = (const float*)d_in[25];
    const float* mb_dtb   = (const float*)d_in[26];
    const float* mb_Al    = (const float*)d_in[27];
    const float* mb_D     = (const float*)d_in[28];
    const float* mb_ow    = (const float*)d_in[29];

    float* ws = (float*)d_ws;
    float* h      = ws;                    // T*DM
    float* xn     = h     + (long)T * DM;  // T*DM
    float* xcres  = xn    + (long)T * DM;  // T*DH
    float* xc     = xcres + (long)T * DH;  // T*DI
    float* xcrev  = xc    + (long)T * DI;  // T*DI
    float* xmz    = xcrev + (long)T * DI;  // 2*T*DH
    float* u      = xmz   + 2L * T * DH;   // 2*T*DI
    float* dtBC   = u     + 2L * T * DI;   // 2*T*64
    float* delta  = dtBC  + 2L * T * 64;   // 2*T*DI
    float* pbuf   = delta + 2L * T * DI;   // 2*T*DI
    float* ycat   = pbuf  + 2L * T * DI;   // T*DH
    float* Pb     = ycat  + (long)T * DH;  // NCH*NSTATE
    float* Qb     = Pb    + (long)NCH * NSTATE;
    float* h0b    = Qb    + (long)NCH * NSTATE;

    // patch embed + cls
    patch_k<<<dim3(50, B), 256, 0, stream>>>(x, patch_w, patch_b, h);
    cls_k<<<dim3(B), 64, 0, stream>>>(cls_tok, h);

    constexpr int GM64  = (T + 63) / 64;    // 32
    constexpr int GM128 = (T + 127) / 128;  // 16

    for (int l = 0; l < LAYERS; ++l) {
        const float* lng = ln_g + (long)l * DM;
        const float* lnb = ln_b + (long)l * DM;
        const float* inw = in_w + (long)l * DH * DM;
        const float* cwl = cw   + (long)l * DI * 4;
        const float* cbl = cb   + (long)l * DI;
        const float* oww = out_w + (long)l * DM * DH;
        const float* fin = mf_in + (long)l * DH * DI;
        const float* bin = mb_in + (long)l * DH * DI;
        const float* fcw = mf_cw + (long)l * DI * 4;
        const float* bcw = mb_cw + (long)l * DI * 4;
        const float* fcb = mf_cb + (long)l * DI;
        const float* bcb = mb_cb + (long)l * DI;
        const float* fxp = mf_xp + (long)l * (RDT + 2 * NST) * DI;
        const float* bxp = mb_xp + (long)l * (RDT + 2 * NST) * DI;
        const float* fdw = mf_dtw + (long)l * DI * RDT;
        const float* bdw = mb_dtw + (long)l * DI * RDT;
        const float* fdb = mf_dtb + (long)l * DI;
        const float* bdb = mb_dtb + (long)l * DI;
        const float* fAl = mf_Al + (long)l * DI * NST;
        const float* bAl = mb_Al + (long)l * DI * NST;
        const float* fD  = mf_D  + (long)l * DI;
        const float* bD  = mb_D  + (long)l * DI;
        const float* fow = mf_ow + (long)l * DI * DI;
        const float* bow = mb_ow + (long)l * DI * DI;

        // xn = LN(h)
        ln_k<<<dim3(T), 64, 0, stream>>>(h, lng, lnb, xn, 1);
        // xcres = xn @ in_w^T  (T x 1024), bf16x3 MFMA
        mgemm_k<128, 128, 0><<<dim3(GM128, DH / 128, 1), 256, 0, stream>>>(
            xn, xn, DM, inw, inw, xcres, 0, DH, nullptr, T, DH, DM);
        // xc = silu(dwconv(xcres[:, :512])) ; xcrev = time-reversed copy
        conv_k<<<dim3(T * DI / 256, 1, 1), 256, 0, stream>>>(
            xcres, xcres, cwl, cwl, cbl, cbl, xc, 0, xcrev);
        // xmz[dir] = (xc|xcrev) @ m{f,b}_in^T  (T x 1024), bf16x3 MFMA
        mgemm_k<128, 128, 0><<<dim3(GM128, DH / 128, 2), 256, 0, stream>>>(
            xc, xcrev, DI, fin, bin, xmz, (long)T * DH, DH, nullptr, T, DH, DI);
        // u[dir] = silu(dwconv(xmz[dir][:, :512]))
        conv_k<<<dim3(T * DI / 256, 1, 2), 256, 0, stream>>>(
            xmz, xmz + (long)T * DH, fcw, bcw, fcb, bcb, u, (long)T * DI, nullptr);
        // dtBC[dir] = u[dir] @ xp^T  (T x 64), fp32
        gemm_k<0><<<dim3(GM64, 1, 2), 256, 0, stream>>>(
            u, u + (long)T * DI, DI, fxp, bxp, nullptr, nullptr, dtBC, (long)T * 64, 64,
            T, 64, DI);
        // delta[dir] = softplus(dt @ dtw^T + dtb)  (T x 512), fp32 (K=32)
        gemm_k<1><<<dim3(GM64, DI / 64, 2), 256, 0, stream>>>(
            dtBC, dtBC + (long)T * 64, 64, fdw, bdw, fdb, bdb, delta, (long)T * DI, DI,
            T, DI, RDT);
        // chunked parallel scan
        scanA_k<<<dim3(B, NCH, 2), 512, 0, stream>>>(delta, dtBC, u, fAl, bAl, Pb, Qb);
        scanB_k<<<dim3(NSTATE / 256), 256, 0, stream>>>(Pb, Qb, h0b);
        scanC_k<<<dim3(B, NCH, 2), 512, 0, stream>>>(
            delta, dtBC, u, xmz, fAl, bAl, fD, bD, h0b, pbuf);
        // ycat = gated out-proj of both dirs, bf16x3 MFMA
        mgemm_k<128, 128, 2><<<dim3(GM128, DI / 128, 2), 256, 0, stream>>>(
            pbuf, pbuf + (long)T * DI, DI, fow, bow, ycat, 0, DH, xcres, T, DI, DI);
        // h = ycat @ out_w^T + h, bf16x3 MFMA (64x64 tile for N=256)
        mgemm_k<64, 64, 3><<<dim3(GM64, DM / 64, 1), 256, 0, stream>>>(
            ycat, ycat, DH, oww, oww, h, 0, DM, h, T, DM, DH);
    }

    // final LN on cls rows only -> d_out (4 x 256)
    ln_k<<<dim3(B), 64, 0, stream>>>(h, fn_g, fn_b, (float*)d_out, S);
}

// Round 5
// 1985.277 us; speedup vs baseline: 2.7248x; 1.2005x over previous
//
#include <hip/hip_runtime.h>
#include <math.h>

// ---- static problem dims ----
constexpr int B   = 4;
constexpr int S   = 501;        // 500 patches + cls
constexpr int T   = B * S;      // 2004 token rows
constexpr int DM  = 256;        // d_model
constexpr int DI  = 512;        // mamba inner dim
constexpr int DH  = 1024;       // 2*DI
constexpr int NST = 16;         // d_state
constexpr int RDT = 32;         // dt_rank
constexpr int LAYERS = 8;

// chunked parallel scan params
constexpr int CS     = 16;                    // time-steps per chunk
constexpr int NCH    = (S + CS - 1) / CS;     // 32 chunks
constexpr int NSTATE = 2 * B * DI * NST;      // 65536 scan states (dir,b,d,n)

// per-layer weight-split segment offsets (elements)
constexpr long WSEG1 = 262144;               // in_w  (1024x256)
constexpr long WSEG2 = WSEG1 + 524288;       // mf_in (1024x512)
constexpr long WSEG3 = WSEG2 + 524288;       // mb_in
constexpr long WSEG4 = WSEG3 + 262144;       // mf_ow (512x512)
constexpr long WSEG5 = WSEG4 + 262144;       // mb_ow
constexpr long WSEGT = WSEG5 + 262144;       // out_w (256x1024) -> total 2097152

constexpr int PK = 1312;                      // patch K 1290 padded to mult of 32

typedef __attribute__((ext_vector_type(8))) short bf16x8;
typedef __attribute__((ext_vector_type(4))) short bf16x4;
typedef __attribute__((ext_vector_type(4))) float f32x4;

__device__ __forceinline__ float silu_f(float x) { return x / (1.0f + expf(-x)); }
__device__ __forceinline__ float softplus_f(float x) { return x > 20.0f ? x : log1pf(expf(x)); }

__device__ __forceinline__ unsigned short f2bf(float f) {
    unsigned u = __float_as_uint(f);
    u += 0x7FFF + ((u >> 16) & 1);          // round-to-nearest-even
    return (unsigned short)(u >> 16);
}
__device__ __forceinline__ float bf2f(unsigned short s) {
    return __uint_as_float((unsigned)s << 16);
}
__device__ __forceinline__ void splitf(float x, unsigned short& h, unsigned short& l) {
    h = f2bf(x);
    l = f2bf(x - bf2f(h));
}

// ---------------- weight split kernels ----------------
// per-layer: 6 tensors -> hi/lo bf16, flat 2097152 elems, grid 1024 x 256thr x 8/thread
__global__ __launch_bounds__(256)
void lsplit_k(const float* __restrict__ s0, const float* __restrict__ s1,
              const float* __restrict__ s2, const float* __restrict__ s3,
              const float* __restrict__ s4, const float* __restrict__ s5,
              unsigned short* __restrict__ hi, unsigned short* __restrict__ lo)
{
    long i = ((long)blockIdx.x * 256 + threadIdx.x) * 8;
    const float* src; long off;
    if      (i < WSEG1) { src = s0; off = 0; }
    else if (i < WSEG2) { src = s1; off = WSEG1; }
    else if (i < WSEG3) { src = s2; off = WSEG2; }
    else if (i < WSEG4) { src = s3; off = WSEG3; }
    else if (i < WSEG5) { src = s4; off = WSEG4; }
    else                { src = s5; off = WSEG5; }
    const float* p = src + (i - off);
    float4 a = ((const float4*)p)[0];
    float4 b4 = ((const float4*)p)[1];
    float v[8] = {a.x, a.y, a.z, a.w, b4.x, b4.y, b4.z, b4.w};
    unsigned short h8[8], l8[8];
#pragma unroll
    for (int j = 0; j < 8; ++j) splitf(v[j], h8[j], l8[j]);
    *(bf16x8*)(hi + i) = *(const bf16x8*)h8;
    *(bf16x8*)(lo + i) = *(const bf16x8*)l8;
}

// patch weights: 256 x 1290 -> padded 256 x 1312 hi/lo. grid 164 x 256 x 8/thread
__global__ __launch_bounds__(256)
void pwsplit_k(const float* __restrict__ pw, unsigned short* __restrict__ hi,
               unsigned short* __restrict__ lo)
{
    long i = ((long)blockIdx.x * 256 + threadIdx.x) * 8;   // < 256*1312, row-mult-of-8 safe
    int row = (int)(i / PK);
    int col = (int)(i - (long)row * PK);
    unsigned short h8[8], l8[8];
#pragma unroll
    for (int j = 0; j < 8; ++j) {
        int cc = col + j;
        float v = (cc < 1290) ? pw[(long)row * 1290 + cc] : 0.0f;
        splitf(v, h8[j], l8[j]);
    }
    *(bf16x8*)(hi + i) = *(const bf16x8*)h8;
    *(bf16x8*)(lo + i) = *(const bf16x8*)l8;
}

// ---------------- patch embed as bf16x3 MFMA GEMM ----------------
// out[p, o] = sum_{c,k} x[b, c, tp*10+k] * pw[o, c*10+k] + pb[o]
// M=2000 (padded 2048), N=256, K=1290 (padded 1312). BM=BN=64, grid (32,4).
__global__ __launch_bounds__(256, 2)
void pgemm_k(const float* __restrict__ x, const unsigned short* __restrict__ PWh,
             const unsigned short* __restrict__ PWl, const float* __restrict__ pb,
             float* __restrict__ h)
{
    constexpr int LDAs = 40;
    __shared__ unsigned short sm[4 * 64 * LDAs];
    unsigned short* Ah_s = sm;
    unsigned short* Al_s = sm + 64 * LDAs;
    unsigned short* Wh_s = sm + 2 * 64 * LDAs;
    unsigned short* Wl_s = sm + 3 * 64 * LDAs;

    const int tid = threadIdx.x;
    const int lane = tid & 63;
    const int wave = tid >> 6;
    const int wr = wave >> 1, wc = wave & 1;
    const int m0 = blockIdx.x * 64, n0 = blockIdx.y * 64;
    const int kl = lane >> 4, rl = lane & 15;

    const int arow = tid >> 2, acs = (tid & 3) * 8;
    const int m = m0 + arow;
    const bool mok = m < 2000;
    const int bq = m / 500, tp = m - bq * 500;
    const float* xb = x + (long)bq * 129 * 5000 + tp * 10;   // + c*5000 + k

    f32x4 acc[2][2];
#pragma unroll
    for (int i = 0; i < 2; ++i)
#pragma unroll
        for (int j = 0; j < 2; ++j) acc[i][j] = (f32x4){0.f, 0.f, 0.f, 0.f};

    for (int k0 = 0; k0 < PK; k0 += 32) {
        // A gather + split (8 scalars/thread)
        unsigned short ah8[8], al8[8];
#pragma unroll
        for (int e = 0; e < 8; ++e) {
            int kk = k0 + acs + e;
            int c = kk / 10, kq = kk - c * 10;
            float v = (mok && kk < 1290) ? xb[(long)c * 5000 + kq] : 0.0f;
            splitf(v, ah8[e], al8[e]);
        }
        *(bf16x8*)(Ah_s + arow * LDAs + acs) = *(const bf16x8*)ah8;
        *(bf16x8*)(Al_s + arow * LDAs + acs) = *(const bf16x8*)al8;
        // W copy (pre-split, padded stride PK)
        {
            long gi = (long)(n0 + arow) * PK + k0 + acs;
            *(bf16x8*)(Wh_s + arow * LDAs + acs) = *(const bf16x8*)(PWh + gi);
            *(bf16x8*)(Wl_s + arow * LDAs + acs) = *(const bf16x8*)(PWl + gi);
        }
        __syncthreads();

        bf16x8 ah[2], al[2], wh[2], wl[2];
#pragma unroll
        for (int i = 0; i < 2; ++i) {
            int r = wr * 32 + i * 16 + rl;
            ah[i] = *(const bf16x8*)&Ah_s[r * LDAs + kl * 8];
            al[i] = *(const bf16x8*)&Al_s[r * LDAs + kl * 8];
        }
#pragma unroll
        for (int j = 0; j < 2; ++j) {
            int r = wc * 32 + j * 16 + rl;
            wh[j] = *(const bf16x8*)&Wh_s[r * LDAs + kl * 8];
            wl[j] = *(const bf16x8*)&Wl_s[r * LDAs + kl * 8];
        }
#pragma unroll
        for (int i = 0; i < 2; ++i)
#pragma unroll
            for (int j = 0; j < 2; ++j) {
                acc[i][j] = __builtin_amdgcn_mfma_f32_16x16x32_bf16(ah[i], wl[j], acc[i][j], 0, 0, 0);
                acc[i][j] = __builtin_amdgcn_mfma_f32_16x16x32_bf16(al[i], wh[j], acc[i][j], 0, 0, 0);
                acc[i][j] = __builtin_amdgcn_mfma_f32_16x16x32_bf16(ah[i], wh[j], acc[i][j], 0, 0, 0);
            }
        __syncthreads();
    }

#pragma unroll
    for (int i = 0; i < 2; ++i)
#pragma unroll
        for (int j = 0; j < 2; ++j) {
            int colg = n0 + wc * 32 + j * 16 + (lane & 15);
            float bias = pb[colg];
            int rbase = m0 + wr * 32 + i * 16 + (lane >> 4) * 4;
#pragma unroll
            for (int r = 0; r < 4; ++r) {
                int mm = rbase + r;
                if (mm >= 2000) continue;
                int bb = mm / 500, tt = mm - bb * 500;
                h[(long)(bb * 501 + 1 + tt) * DM + colg] = acc[i][j][r] + bias;
            }
        }
}

// grid (B), 64 threads: write cls row
__global__ __launch_bounds__(64)
void cls_k(const float* __restrict__ cls, float* __restrict__ h)
{
    int b = blockIdx.x, lane = threadIdx.x;
    ((float4*)(h + (long)b * S * DM))[lane] = ((const float4*)cls)[lane];
}

// ---------------- layernorm over 256: one wave per row ----------------
// SPLIT=true: write hi/lo bf16 (feeds MFMA GEMM). SPLIT=false: fp32 out (final LN).
template<bool SPLIT>
__global__ __launch_bounds__(64)
void ln_k(const float* __restrict__ hin, const float* __restrict__ g,
          const float* __restrict__ be, float* __restrict__ outf,
          unsigned short* __restrict__ oh, unsigned short* __restrict__ ol, int rowMul)
{
    long hr = (long)blockIdx.x * rowMul;
    int lane = threadIdx.x;
    float4 v = ((const float4*)(hin + hr * DM))[lane];
    float s = v.x + v.y + v.z + v.w;
    float q = v.x * v.x + v.y * v.y + v.z * v.z + v.w * v.w;
#pragma unroll
    for (int off = 32; off; off >>= 1) { s += __shfl_xor(s, off); q += __shfl_xor(q, off); }
    float mean = s * (1.0f / DM);
    float var  = q * (1.0f / DM) - mean * mean;
    float rs = rsqrtf(var + 1e-5f);
    float4 gg = ((const float4*)g)[lane];
    float4 bb = ((const float4*)be)[lane];
    float o[4];
    o[0] = (v.x - mean) * rs * gg.x + bb.x;
    o[1] = (v.y - mean) * rs * gg.y + bb.y;
    o[2] = (v.z - mean) * rs * gg.z + bb.z;
    o[3] = (v.w - mean) * rs * gg.w + bb.w;
    if constexpr (SPLIT) {
        unsigned short h4[4], l4[4];
#pragma unroll
        for (int j = 0; j < 4; ++j) splitf(o[j], h4[j], l4[j]);
        long idx = (long)blockIdx.x * DM + lane * 4;
        *(bf16x4*)(oh + idx) = *(const bf16x4*)h4;
        *(bf16x4*)(ol + idx) = *(const bf16x4*)l4;
    } else {
        ((float4*)(outf + (long)blockIdx.x * DM))[lane] = make_float4(o[0], o[1], o[2], o[3]);
    }
}

// ---------------- bf16x3 MFMA GEMM with pre-split hi/lo inputs ----------------
// C[m,n] = sum_k A[m,k]*W[n,k]; A,W given as hi/lo bf16 arrays. BK=32, 4 waves.
// EPI: 0=plain fp32 store, 2=gate-cat (bf16 hi/lo out + flip + silu gate), 3=residual add
template<int BM, int BN, int EPI>
__global__ __launch_bounds__(256, 2)
void mgemm_k(const unsigned short* __restrict__ Ah0, const unsigned short* __restrict__ Al0,
             const unsigned short* __restrict__ Ah1, const unsigned short* __restrict__ Al1,
             int lda,
             const unsigned short* __restrict__ Wh0, const unsigned short* __restrict__ Wl0,
             const unsigned short* __restrict__ Wh1, const unsigned short* __restrict__ Wl1,
             float* __restrict__ Cout, long cStrideZ, int ldc,
             const float* __restrict__ resid,
             unsigned short* __restrict__ Oh, unsigned short* __restrict__ Ol,
             int M, int N, int K)
{
    constexpr int MI = BM / 32;
    constexpr int NJ = BN / 32;
    constexpr int LDAs = 40;

    __shared__ unsigned short sm[(2 * BM + 2 * BN) * LDAs];
    unsigned short* Ah_s = sm;
    unsigned short* Al_s = sm + BM * LDAs;
    unsigned short* Wh_s = sm + 2 * BM * LDAs;
    unsigned short* Wl_s = sm + 2 * BM * LDAs + BN * LDAs;

    const int dir = blockIdx.z;
    const unsigned short* __restrict__ A_h = dir ? Ah1 : Ah0;
    const unsigned short* __restrict__ A_l = dir ? Al1 : Al0;
    const unsigned short* __restrict__ W_h = dir ? Wh1 : Wh0;
    const unsigned short* __restrict__ W_l = dir ? Wl1 : Wl0;
    const int tid = threadIdx.x;
    const int lane = tid & 63;
    const int wave = tid >> 6;
    const int wr = wave >> 1, wc = wave & 1;
    const int m0 = blockIdx.x * BM, n0 = blockIdx.y * BN;
    const int kl = lane >> 4, rl = lane & 15;

    f32x4 acc[MI][NJ];
#pragma unroll
    for (int i = 0; i < MI; ++i)
#pragma unroll
        for (int j = 0; j < NJ; ++j) acc[i][j] = (f32x4){0.f, 0.f, 0.f, 0.f};

    const bf16x8 zv = {0, 0, 0, 0, 0, 0, 0, 0};

    for (int k0 = 0; k0 < K; k0 += 32) {
        if constexpr (BM == 128) {
            int row = tid >> 1, cs = (tid & 1) * 16;
            {
                bool ok = (m0 + row) < M;
                long gi = (long)(m0 + row) * lda + k0 + cs;
                bf16x8 h0 = zv, h1 = zv, l0 = zv, l1 = zv;
                if (ok) {
                    h0 = *(const bf16x8*)(A_h + gi);
                    h1 = *(const bf16x8*)(A_h + gi + 8);
                    l0 = *(const bf16x8*)(A_l + gi);
                    l1 = *(const bf16x8*)(A_l + gi + 8);
                }
                *(bf16x8*)(Ah_s + row * LDAs + cs) = h0;
                *(bf16x8*)(Ah_s + row * LDAs + cs + 8) = h1;
                *(bf16x8*)(Al_s + row * LDAs + cs) = l0;
                *(bf16x8*)(Al_s + row * LDAs + cs + 8) = l1;
            }
            {
                long gi = (long)(n0 + row) * K + k0 + cs;
                *(bf16x8*)(Wh_s + row * LDAs + cs)     = *(const bf16x8*)(W_h + gi);
                *(bf16x8*)(Wh_s + row * LDAs + cs + 8) = *(const bf16x8*)(W_h + gi + 8);
                *(bf16x8*)(Wl_s + row * LDAs + cs)     = *(const bf16x8*)(W_l + gi);
                *(bf16x8*)(Wl_s + row * LDAs + cs + 8) = *(const bf16x8*)(W_l + gi + 8);
            }
        } else {   // BM==BN==64: threads 0..127 stage A, 128..255 stage W
            int t2 = tid & 127;
            int row = t2 >> 1, cs = (t2 & 1) * 16;
            if (tid < 128) {
                bool ok = (m0 + row) < M;
                long gi = (long)(m0 + row) * lda + k0 + cs;
                bf16x8 h0 = zv, h1 = zv, l0 = zv, l1 = zv;
                if (ok) {
                    h0 = *(const bf16x8*)(A_h + gi);
                    h1 = *(const bf16x8*)(A_h + gi + 8);
                    l0 = *(const bf16x8*)(A_l + gi);
                    l1 = *(const bf16x8*)(A_l + gi + 8);
                }
                *(bf16x8*)(Ah_s + row * LDAs + cs) = h0;
                *(bf16x8*)(Ah_s + row * LDAs + cs + 8) = h1;
                *(bf16x8*)(Al_s + row * LDAs + cs) = l0;
                *(bf16x8*)(Al_s + row * LDAs + cs + 8) = l1;
            } else {
                long gi = (long)(n0 + row) * K + k0 + cs;
                *(bf16x8*)(Wh_s + row * LDAs + cs)     = *(const bf16x8*)(W_h + gi);
                *(bf16x8*)(Wh_s + row * LDAs + cs + 8) = *(const bf16x8*)(W_h + gi + 8);
                *(bf16x8*)(Wl_s + row * LDAs + cs)     = *(const bf16x8*)(W_l + gi);
                *(bf16x8*)(Wl_s + row * LDAs + cs + 8) = *(const bf16x8*)(W_l + gi + 8);
            }
        }
        __syncthreads();

        bf16x8 ah[MI], al[MI], wh[NJ], wl[NJ];
#pragma unroll
        for (int i = 0; i < MI; ++i) {
            int r = wr * (BM / 2) + i * 16 + rl;
            ah[i] = *(const bf16x8*)&Ah_s[r * LDAs + kl * 8];
            al[i] = *(const bf16x8*)&Al_s[r * LDAs + kl * 8];
        }
#pragma unroll
        for (int j = 0; j < NJ; ++j) {
            int r = wc * (BN / 2) + j * 16 + rl;
            wh[j] = *(const bf16x8*)&Wh_s[r * LDAs + kl * 8];
            wl[j] = *(const bf16x8*)&Wl_s[r * LDAs + kl * 8];
        }
#pragma unroll
        for (int i = 0; i < MI; ++i)
#pragma unroll
            for (int j = 0; j < NJ; ++j) {
                acc[i][j] = __builtin_amdgcn_mfma_f32_16x16x32_bf16(ah[i], wl[j], acc[i][j], 0, 0, 0);
                acc[i][j] = __builtin_amdgcn_mfma_f32_16x16x32_bf16(al[i], wh[j], acc[i][j], 0, 0, 0);
                acc[i][j] = __builtin_amdgcn_mfma_f32_16x16x32_bf16(ah[i], wh[j], acc[i][j], 0, 0, 0);
            }
        __syncthreads();
    }

    float* C = Cout + (long)dir * cStrideZ;
#pragma unroll
    for (int i = 0; i < MI; ++i) {
#pragma unroll
        for (int j = 0; j < NJ; ++j) {
            int rbase = m0 + wr * (BM / 2) + i * 16 + (lane >> 4) * 4;
            int colg = n0 + wc * (BN / 2) + j * 16 + (lane & 15);
#pragma unroll
            for (int r = 0; r < 4; ++r) {
                int rowg = rbase + r;
                if (rowg >= M) continue;
                float val = acc[i][j][r];
                if constexpr (EPI == 0) {
                    C[(long)rowg * ldc + colg] = val;
                } else if constexpr (EPI == 2) {
                    int bb = rowg / S;
                    int t  = rowg - bb * S;
                    long rt = dir ? (long)(bb * S + (S - 1 - t)) : (long)rowg;
                    float g = resid[rt * DH + DI + colg];
                    float o = val * silu_f(g);
                    unsigned short hh, ll;
                    splitf(o, hh, ll);
                    Oh[rt * DH + (dir ? DI : 0) + colg] = hh;
                    Ol[rt * DH + (dir ? DI : 0) + colg] = ll;
                } else {   // EPI == 3
                    C[(long)rowg * ldc + colg] = val + resid[(long)rowg * ldc + colg];
                }
            }
        }
    }
}

// ---------------- fp32 GEMM for small shapes (xp N=64, dtw K=32) ----------------
// EPI: 0=plain store, 1=bias+softplus
template<int EPI>
__global__ __launch_bounds__(256)
void gemm_k(const float* __restrict__ A0, const float* __restrict__ A1, int lda,
            const float* __restrict__ W0, const float* __restrict__ W1,
            const float* __restrict__ b0, const float* __restrict__ b1,
            float* __restrict__ Cout, long cStrideZ, int ldc,
            int M, int N, int K)
{
    const int dir = blockIdx.z;
    const float* __restrict__ A = dir ? A1 : A0;
    const float* __restrict__ W = dir ? W1 : W0;
    __shared__ float As[16][64];
    __shared__ float Ws[16][64];
    const int tid = threadIdx.x;
    const int tx = tid & 15, ty = tid >> 4;
    const int m0 = blockIdx.x * 64, n0 = blockIdx.y * 64;
    const int arow = tid >> 2;
    const int acol = (tid & 3) * 4;
    float acc[4][4] = {};

    for (int k0 = 0; k0 < K; k0 += 16) {
        {
            int row = m0 + arow;
            float4 va = make_float4(0.f, 0.f, 0.f, 0.f);
            if (row < M) va = *(const float4*)(A + (long)row * lda + k0 + acol);
            As[acol + 0][arow] = va.x; As[acol + 1][arow] = va.y;
            As[acol + 2][arow] = va.z; As[acol + 3][arow] = va.w;
            float4 vw = *(const float4*)(W + (long)(n0 + arow) * K + k0 + acol);
            Ws[acol + 0][arow] = vw.x; Ws[acol + 1][arow] = vw.y;
            Ws[acol + 2][arow] = vw.z; Ws[acol + 3][arow] = vw.w;
        }
        __syncthreads();
#pragma unroll
        for (int kk = 0; kk < 16; ++kk) {
            float4 av = *(const float4*)&As[kk][ty * 4];
            float4 wv = *(const float4*)&Ws[kk][tx * 4];
            float a[4] = {av.x, av.y, av.z, av.w};
            float w[4] = {wv.x, wv.y, wv.z, wv.w};
#pragma unroll
            for (int i = 0; i < 4; ++i)
#pragma unroll
                for (int j = 0; j < 4; ++j)
                    acc[i][j] = fmaf(a[i], w[j], acc[i][j]);
        }
        __syncthreads();
    }

    const float* bias = dir ? b1 : b0;
    float* C = Cout + (long)dir * cStrideZ;
#pragma unroll
    for (int i = 0; i < 4; ++i) {
        int row = m0 + ty * 4 + i;
        if (row >= M) continue;
        int col = n0 + tx * 4;
        if constexpr (EPI == 0) {
            float4 v = make_float4(acc[i][0], acc[i][1], acc[i][2], acc[i][3]);
            *(float4*)(C + (long)row * ldc + col) = v;
        } else {
            float4 b4 = *(const float4*)(bias + col);
            float4 v;
            v.x = softplus_f(acc[i][0] + b4.x);
            v.y = softplus_f(acc[i][1] + b4.y);
            v.z = softplus_f(acc[i][2] + b4.z);
            v.w = softplus_f(acc[i][3] + b4.w);
            *(float4*)(C + (long)row * ldc + col) = v;
        }
    }
}

// ---------------- causal depthwise conv (K=4) + silu ----------------
// MODE 0: write bf16 hi/lo (out + time-reversed copy), single dir.
// MODE 1: write fp32, dual dir via blockIdx.z.
template<int MODE>
__global__ __launch_bounds__(256)
void conv_k(const float* __restrict__ in0, const float* __restrict__ in1,
            const float* __restrict__ cw0, const float* __restrict__ cw1,
            const float* __restrict__ cb0, const float* __restrict__ cb1,
            float* __restrict__ outf, long outStrideZ,
            unsigned short* __restrict__ oh, unsigned short* __restrict__ ol,
            unsigned short* __restrict__ orh, unsigned short* __restrict__ orl)
{
    const int dir = blockIdx.z;
    const float* __restrict__ in = dir ? in1 : in0;
    const float* __restrict__ cw = dir ? cw1 : cw0;
    const float* __restrict__ cb = dir ? cb1 : cb0;
    int idx = blockIdx.x * 256 + threadIdx.x;
    if (idx >= T * DI) return;
    int d = idx & (DI - 1);
    int r = idx >> 9;
    int b = r / S, t = r - b * S;
    float acc = cb[d];
#pragma unroll
    for (int k = 0; k < 4; ++k) {
        int tt = t - 3 + k;
        if (tt >= 0) acc = fmaf(cw[d * 4 + k], in[(long)(b * S + tt) * DH + d], acc);
    }
    acc = silu_f(acc);
    if constexpr (MODE == 0) {
        unsigned short hh, ll;
        splitf(acc, hh, ll);
        long i0 = (long)r * DI + d;
        long i1 = (long)(b * S + (S - 1 - t)) * DI + d;
        oh[i0] = hh;  ol[i0] = ll;
        orh[i1] = hh; orl[i1] = ll;
    } else {
        (outf + (long)dir * outStrideZ)[(long)r * DI + d] = acc;
    }
}

// ---------------- chunked parallel selective scan ----------------
__global__ __launch_bounds__(512)
void scanA_k(const float* __restrict__ delta, const float* __restrict__ dtBC,
             const float* __restrict__ u,
             const float* __restrict__ Al0, const float* __restrict__ Al1,
             float* __restrict__ Pb, float* __restrict__ Qb)
{
    __shared__ float B_s[CS * 16];
    const int b = blockIdx.x, c = blockIdx.y, dir = blockIdx.z;
    const int d = threadIdx.x;
    const int c0 = c * CS;
    const int tt = min(CS, S - c0);

    const float* dl  = delta + (long)dir * T * DI + (long)b * S * DI;
    const float* bcp = dtBC  + (long)dir * T * 64 + (long)b * S * 64;
    const float* uu  = u     + (long)dir * T * DI + (long)b * S * DI;

    if (threadIdx.x < CS * 16) {
        int t = threadIdx.x >> 4, n = threadIdx.x & 15;
        B_s[threadIdx.x] = (t < tt) ? bcp[(long)(c0 + t) * 64 + RDT + n] : 0.f;
    }
    __syncthreads();

    const float* Al = dir ? Al1 : Al0;
    float A2[16], Pv[16], Qv[16];
#pragma unroll
    for (int i = 0; i < 4; ++i) {
        float4 a4 = *(const float4*)(Al + (long)d * NST + 4 * i);
        A2[4 * i + 0] = -__expf(a4.x);
        A2[4 * i + 1] = -__expf(a4.y);
        A2[4 * i + 2] = -__expf(a4.z);
        A2[4 * i + 3] = -__expf(a4.w);
    }
#pragma unroll
    for (int n = 0; n < 16; ++n) { Pv[n] = 1.0f; Qv[n] = 0.0f; }

#pragma unroll 2
    for (int t = 0; t < tt; ++t) {
        float dv = dl[(long)(c0 + t) * DI + d];
        float uv = uu[(long)(c0 + t) * DI + d];
        float dvu = dv * uv;
#pragma unroll
        for (int n = 0; n < 16; ++n) {
            float a = __expf(dv * A2[n]);
            Pv[n] *= a;
            Qv[n] = fmaf(a, Qv[n], dvu * B_s[t * 16 + n]);
        }
    }

    long st0 = ((long)(dir * B + b) * DI + d) * NST;
    long co  = (long)c * NSTATE;
#pragma unroll
    for (int i = 0; i < 4; ++i) {
        *(float4*)(Pb + co + st0 + 4 * i) =
            make_float4(Pv[4 * i], Pv[4 * i + 1], Pv[4 * i + 2], Pv[4 * i + 3]);
        *(float4*)(Qb + co + st0 + 4 * i) =
            make_float4(Qv[4 * i], Qv[4 * i + 1], Qv[4 * i + 2], Qv[4 * i + 3]);
    }
}

__global__ __launch_bounds__(256)
void scanB_k(const float* __restrict__ Pb, const float* __restrict__ Qb,
             float* __restrict__ h0)
{
    const int st = blockIdx.x * 256 + threadIdx.x;
    float Pv[NCH], Qv[NCH];
#pragma unroll
    for (int c = 0; c < NCH; ++c) {
        Pv[c] = Pb[(long)c * NSTATE + st];
        Qv[c] = Qb[(long)c * NSTATE + st];
    }
    float h = 0.0f;
#pragma unroll
    for (int c = 0; c < NCH; ++c) {
        h0[(long)c * NSTATE + st] = h;
        h = fmaf(Pv[c], h, Qv[c]);
    }
}

// Phase C: replay chunk; emits p as bf16 hi/lo (feeds ow MFMA GEMM).
__global__ __launch_bounds__(512)
void scanC_k(const float* __restrict__ delta, const float* __restrict__ dtBC,
             const float* __restrict__ u, const float* __restrict__ xmz,
             const float* __restrict__ Al0, const float* __restrict__ Al1,
             const float* __restrict__ D0, const float* __restrict__ D1,
             const float* __restrict__ h0,
             unsigned short* __restrict__ ph, unsigned short* __restrict__ pl)
{
    __shared__ float BC_s[CS * 32];
    const int b = blockIdx.x, c = blockIdx.y, dir = blockIdx.z;
    const int d = threadIdx.x;
    const int c0 = c * CS;
    const int tt = min(CS, S - c0);

    const float* dl  = delta + (long)dir * T * DI + (long)b * S * DI;
    const float* bcp = dtBC  + (long)dir * T * 64 + (long)b * S * 64;
    const float* uu  = u     + (long)dir * T * DI + (long)b * S * DI;
    const float* zz  = xmz   + (long)dir * T * DH + (long)b * S * DH + DI;
    unsigned short* poh = ph + (long)dir * T * DI + (long)b * S * DI;
    unsigned short* pol = pl + (long)dir * T * DI + (long)b * S * DI;

    {
        int t = threadIdx.x >> 5, j = threadIdx.x & 31;
        BC_s[threadIdx.x] = (t < tt) ? bcp[(long)(c0 + t) * 64 + RDT + j] : 0.f;
    }
    __syncthreads();

    const float* Al = dir ? Al1 : Al0;
    float A2[16], hv[16];
#pragma unroll
    for (int i = 0; i < 4; ++i) {
        float4 a4 = *(const float4*)(Al + (long)d * NST + 4 * i);
        A2[4 * i + 0] = -__expf(a4.x);
        A2[4 * i + 1] = -__expf(a4.y);
        A2[4 * i + 2] = -__expf(a4.z);
        A2[4 * i + 3] = -__expf(a4.w);
    }
    long st0 = ((long)(dir * B + b) * DI + d) * NST;
#pragma unroll
    for (int i = 0; i < 4; ++i) {
        float4 h4 = *(const float4*)(h0 + (long)c * NSTATE + st0 + 4 * i);
        hv[4 * i + 0] = h4.x; hv[4 * i + 1] = h4.y;
        hv[4 * i + 2] = h4.z; hv[4 * i + 3] = h4.w;
    }
    const float Dp = (dir ? D1 : D0)[d];

#pragma unroll 2
    for (int t = 0; t < tt; ++t) {
        float dv = dl[(long)(c0 + t) * DI + d];
        float uv = uu[(long)(c0 + t) * DI + d];
        float zv = zz[(long)(c0 + t) * DH + d];
        float dvu = dv * uv;
        float y = 0.0f;
#pragma unroll
        for (int n = 0; n < 16; ++n) {
            float a = __expf(dv * A2[n]);
            hv[n] = fmaf(a, hv[n], dvu * BC_s[t * 32 + n]);
            y = fmaf(hv[n], BC_s[t * 32 + 16 + n], y);
        }
        float sz = zv / (1.0f + __expf(-zv));
        float o = (y + uv * Dp) * sz;
        unsigned short hh, ll;
        splitf(o, hh, ll);
        poh[(long)(c0 + t) * DI + d] = hh;
        pol[(long)(c0 + t) * DI + d] = ll;
    }
}

// ---------------- host orchestration ----------------
extern "C" void kernel_launch(void* const* d_in, const int* in_sizes, int n_in,
                              void* d_out, int out_size, void* d_ws, size_t ws_size,
                              hipStream_t stream)
{
    (void)in_sizes; (void)n_in; (void)out_size; (void)ws_size;
    const float* x        = (const float*)d_in[0];
    const float* patch_w  = (const float*)d_in[1];
    const float* patch_b  = (const float*)d_in[2];
    const float* cls_tok  = (const float*)d_in[3];
    const float* ln_g     = (const float*)d_in[4];
    const float* ln_b     = (const float*)d_in[5];
    const float* in_w     = (const float*)d_in[6];
    const float* cw       = (const float*)d_in[7];
    const float* cb       = (const float*)d_in[8];
    const float* out_w    = (const float*)d_in[9];
    const float* fn_g     = (const float*)d_in[10];
    const float* fn_b     = (const float*)d_in[11];
    const float* mf_in    = (const float*)d_in[12];
    const float* mf_cw    = (const float*)d_in[13];
    const float* mf_cb    = (const float*)d_in[14];
    const float* mf_xp    = (const float*)d_in[15];
    const float* mf_dtw   = (const float*)d_in[16];
    const float* mf_dtb   = (const float*)d_in[17];
    const float* mf_Al    = (const float*)d_in[18];
    const float* mf_D     = (const float*)d_in[19];
    const float* mf_ow    = (const float*)d_in[20];
    const float* mb_in    = (const float*)d_in[21];
    const float* mb_cw    = (const float*)d_in[22];
    const float* mb_cb    = (const float*)d_in[23];
    const float* mb_xp    = (const float*)d_in[24];
    const float* mb_dtw   = (const float*)d_in[25];
    const float* mb_dtb   = (const float*)d_in[26];
    const float* mb_Al    = (const float*)d_in[27];
    const float* mb_D     = (const float*)d_in[28];
    const float* mb_ow    = (const float*)d_in[29];

    float* ws = (float*)d_ws;
    float* h      = ws;                    // T*DM
    float* xcres  = h     + (long)T * DM;  // T*DH
    float* xmz    = xcres + (long)T * DH;  // 2*T*DH
    float* u      = xmz   + 2L * T * DH;   // 2*T*DI
    float* dtBC   = u     + 2L * T * DI;   // 2*T*64
    float* delta  = dtBC  + 2L * T * 64;   // 2*T*DI
    float* Pb     = delta + 2L * T * DI;   // NCH*NSTATE
    float* Qb     = Pb    + (long)NCH * NSTATE;
    float* h0b    = Qb    + (long)NCH * NSTATE;
    unsigned short* us = (unsigned short*)(h0b + (long)NCH * NSTATE);
    unsigned short* xnh  = us;                       // T*DM
    unsigned short* xnl  = xnh + (long)T * DM;
    unsigned short* xch  = xnl + (long)T * DM;       // T*DI
    unsigned short* xcl  = xch + (long)T * DI;
    unsigned short* xrvh = xcl + (long)T * DI;
    unsigned short* xrvl = xrvh + (long)T * DI;
    unsigned short* ph   = xrvl + (long)T * DI;      // 2*T*DI
    unsigned short* pl   = ph   + 2L * T * DI;
    unsigned short* ych  = pl   + 2L * T * DI;       // T*DH
    unsigned short* ycl  = ych  + (long)T * DH;
    unsigned short* WH   = ycl  + (long)T * DH;      // 2097152 (per-layer, reused)
    unsigned short* WL   = WH   + WSEGT;
    unsigned short* PWH  = WL   + WSEGT;             // 256*PK
    unsigned short* PWL  = PWH  + 256L * PK;

    // per-layer weight-split slice pointers (offsets into WH/WL)
    const long o_inw = 0, o_fin = WSEG1, o_bin = WSEG2, o_fow = WSEG3,
               o_bow = WSEG4, o_oww = WSEG5;

    // patch embed: pre-split patch weights, MFMA GEMM, cls row
    pwsplit_k<<<dim3(256 * PK / 2048), 256, 0, stream>>>(patch_w, PWH, PWL);
    pgemm_k<<<dim3(32, 4), 256, 0, stream>>>(x, PWH, PWL, patch_b, h);
    cls_k<<<dim3(B), 64, 0, stream>>>(cls_tok, h);

    constexpr int GM64  = (T + 63) / 64;    // 32
    constexpr int GM128 = (T + 127) / 128;  // 16

    for (int l = 0; l < LAYERS; ++l) {
        const float* lng = ln_g + (long)l * DM;
        const float* lnb = ln_b + (long)l * DM;
        const float* inw = in_w + (long)l * DH * DM;
        const float* cwl = cw   + (long)l * DI * 4;
        const float* cbl = cb   + (long)l * DI;
        const float* oww = out_w + (long)l * DM * DH;
        const float* fin = mf_in + (long)l * DH * DI;
        const float* bin = mb_in + (long)l * DH * DI;
        const float* fcw = mf_cw + (long)l * DI * 4;
        const float* bcw = mb_cw + (long)l * DI * 4;
        const float* fcb = mf_cb + (long)l * DI;
        const float* bcb = mb_cb + (long)l * DI;
        const float* fxp = mf_xp + (long)l * (RDT + 2 * NST) * DI;
        const float* bxp = mb_xp + (long)l * (RDT + 2 * NST) * DI;
        const float* fdw = mf_dtw + (long)l * DI * RDT;
        const float* bdw = mb_dtw + (long)l * DI * RDT;
        const float* fdb = mf_dtb + (long)l * DI;
        const float* bdb = mb_dtb + (long)l * DI;
        const float* fAl = mf_Al + (long)l * DI * NST;
        const float* bAl = mb_Al + (long)l * DI * NST;
        const float* fD  = mf_D  + (long)l * DI;
        const float* bD  = mb_D  + (long)l * DI;
        const float* fow = mf_ow + (long)l * DI * DI;
        const float* bow = mb_ow + (long)l * DI * DI;

        // split this layer's big weights to hi/lo bf16 (one segmented kernel)
        lsplit_k<<<dim3(WSEGT / 2048), 256, 0, stream>>>(inw, fin, bin, fow, bow, oww, WH, WL);

        // xn(hi/lo) = LN(h)
        ln_k<true><<<dim3(T), 64, 0, stream>>>(h, lng, lnb, nullptr, xnh, xnl, 1);
        // xcres = xn @ in_w^T  (T x 1024)
        mgemm_k<128, 128, 0><<<dim3(GM128, DH / 128, 1), 256, 0, stream>>>(
            xnh, xnl, xnh, xnl, DM, WH + o_inw, WL + o_inw, WH + o_inw, WL + o_inw,
            xcres, 0, DH, nullptr, nullptr, nullptr, T, DH, DM);
        // xc(hi/lo) = silu(dwconv(xcres[:, :512])), + time-reversed copy
        conv_k<0><<<dim3(T * DI / 256, 1, 1), 256, 0, stream>>>(
            xcres, xcres, cwl, cwl, cbl, cbl, nullptr, 0, xch, xcl, xrvh, xrvl);
        // xmz[dir] = (xc|xcrev) @ m{f,b}_in^T  (T x 1024)
        mgemm_k<128, 128, 0><<<dim3(GM128, DH / 128, 2), 256, 0, stream>>>(
            xch, xcl, xrvh, xrvl, DI, WH + o_fin, WL + o_fin, WH + o_bin, WL + o_bin,
            xmz, (long)T * DH, DH, nullptr, nullptr, nullptr, T, DH, DI);
        // u[dir] = silu(dwconv(xmz[dir][:, :512]))  (fp32, scan needs it)
        conv_k<1><<<dim3(T * DI / 256, 1, 2), 256, 0, stream>>>(
            xmz, xmz + (long)T * DH, fcw, bcw, fcb, bcb, u, (long)T * DI,
            nullptr, nullptr, nullptr, nullptr);
        // dtBC[dir] = u[dir] @ xp^T  (T x 64), fp32
        gemm_k<0><<<dim3(GM64, 1, 2), 256, 0, stream>>>(
            u, u + (long)T * DI, DI, fxp, bxp, nullptr, nullptr, dtBC, (long)T * 64, 64,
            T, 64, DI);
        // delta[dir] = softplus(dt @ dtw^T + dtb)  (T x 512), fp32 (K=32)
        gemm_k<1><<<dim3(GM64, DI / 64, 2), 256, 0, stream>>>(
            dtBC, dtBC + (long)T * 64, 64, fdw, bdw, fdb, bdb, delta, (long)T * DI, DI,
            T, DI, RDT);
        // chunked parallel scan (C emits p as hi/lo bf16)
        scanA_k<<<dim3(B, NCH, 2), 512, 0, stream>>>(delta, dtBC, u, fAl, bAl, Pb, Qb);
        scanB_k<<<dim3(NSTATE / 256), 256, 0, stream>>>(Pb, Qb, h0b);
        scanC_k<<<dim3(B, NCH, 2), 512, 0, stream>>>(
            delta, dtBC, u, xmz, fAl, bAl, fD, bD, h0b, ph, pl);
        // ycat(hi/lo) = gated out-proj of both dirs (flip-scatter + silu gate)
        mgemm_k<128, 128, 2><<<dim3(GM128, DI / 128, 2), 256, 0, stream>>>(
            ph, pl, ph + (long)T * DI, pl + (long)T * DI, DI,
            WH + o_fow, WL + o_fow, WH + o_bow, WL + o_bow,
            nullptr, 0, DH, xcres, ych, ycl, T, DI, DI);
        // h = ycat @ out_w^T + h
        mgemm_k<64, 64, 3><<<dim3(GM64, DM / 64, 1), 256, 0, stream>>>(
            ych, ycl, ych, ycl, DH, WH + o_oww, WL + o_oww, WH + o_oww, WL + o_oww,
            h, 0, DM, h, nullptr, nullptr, T, DM, DH);
    }

    // final LN on cls rows only -> d_out (4 x 256)
    ln_k<false><<<dim3(B), 64, 0, stream>>>(h, fn_g, fn_b, (float*)d_out, nullptr, nullptr, S);
}

// Round 6
// 1831.217 us; speedup vs baseline: 2.9540x; 1.0841x over previous
//
#include <hip/hip_runtime.h>
#include <math.h>

// ---- static problem dims ----
constexpr int B   = 4;
constexpr int S   = 501;        // 500 patches + cls
constexpr int T   = B * S;      // 2004 token rows
constexpr int DM  = 256;        // d_model
constexpr int DI  = 512;        // mamba inner dim
constexpr int DH  = 1024;       // 2*DI
constexpr int NST = 16;         // d_state
constexpr int RDT = 32;         // dt_rank
constexpr int LAYERS = 8;

// chunked parallel scan params
constexpr int CS     = 16;                    // time-steps per chunk
constexpr int NCH    = (S + CS - 1) / CS;     // 32 chunks
constexpr int NSTATE = 2 * B * DI * NST;      // 65536 scan states (dir,b,d,n)

// per-layer weight-split segment offsets (elements)
constexpr long WSEG1 = 262144;               // in_w  (1024x256)
constexpr long WSEG2 = WSEG1 + 524288;       // mf_in (1024x512)
constexpr long WSEG3 = WSEG2 + 524288;       // mb_in
constexpr long WSEG4 = WSEG3 + 262144;       // mf_ow (512x512)
constexpr long WSEG5 = WSEG4 + 262144;       // mb_ow
constexpr long WSEGT = WSEG5 + 262144;       // out_w (256x1024) -> total 2097152

constexpr int PK = 1312;                      // patch K 1290 padded to mult of 32
constexpr int PM = 2000;                      // patch rows

typedef __attribute__((ext_vector_type(8))) short bf16x8;
typedef __attribute__((ext_vector_type(4))) short bf16x4;
typedef __attribute__((ext_vector_type(4))) float f32x4;

__device__ __forceinline__ float silu_f(float x) { return x / (1.0f + expf(-x)); }
__device__ __forceinline__ float softplus_f(float x) { return x > 20.0f ? x : log1pf(expf(x)); }

__device__ __forceinline__ unsigned short f2bf(float f) {
    unsigned u = __float_as_uint(f);
    u += 0x7FFF + ((u >> 16) & 1);          // round-to-nearest-even
    return (unsigned short)(u >> 16);
}
__device__ __forceinline__ float bf2f(unsigned short s) {
    return __uint_as_float((unsigned)s << 16);
}
__device__ __forceinline__ void splitf(float x, unsigned short& h, unsigned short& l) {
    h = f2bf(x);
    l = f2bf(x - bf2f(h));
}

// ---------------- weight split kernels ----------------
__global__ __launch_bounds__(256)
void lsplit_k(const float* __restrict__ s0, const float* __restrict__ s1,
              const float* __restrict__ s2, const float* __restrict__ s3,
              const float* __restrict__ s4, const float* __restrict__ s5,
              unsigned short* __restrict__ hi, unsigned short* __restrict__ lo)
{
    long i = ((long)blockIdx.x * 256 + threadIdx.x) * 8;
    const float* src; long off;
    if      (i < WSEG1) { src = s0; off = 0; }
    else if (i < WSEG2) { src = s1; off = WSEG1; }
    else if (i < WSEG3) { src = s2; off = WSEG2; }
    else if (i < WSEG4) { src = s3; off = WSEG3; }
    else if (i < WSEG5) { src = s4; off = WSEG4; }
    else                { src = s5; off = WSEG5; }
    const float* p = src + (i - off);
    float4 a = ((const float4*)p)[0];
    float4 b4 = ((const float4*)p)[1];
    float v[8] = {a.x, a.y, a.z, a.w, b4.x, b4.y, b4.z, b4.w};
    unsigned short h8[8], l8[8];
#pragma unroll
    for (int j = 0; j < 8; ++j) splitf(v[j], h8[j], l8[j]);
    *(bf16x8*)(hi + i) = *(const bf16x8*)h8;
    *(bf16x8*)(lo + i) = *(const bf16x8*)l8;
}

// patch weights: 256 x 1290 -> padded 256 x 1312 hi/lo
__global__ __launch_bounds__(256)
void pwsplit_k(const float* __restrict__ pw, unsigned short* __restrict__ hi,
               unsigned short* __restrict__ lo)
{
    long i = ((long)blockIdx.x * 256 + threadIdx.x) * 8;
    int row = (int)(i / PK);
    int col = (int)(i - (long)row * PK);
    unsigned short h8[8], l8[8];
#pragma unroll
    for (int j = 0; j < 8; ++j) {
        int cc = col + j;
        float v = (cc < 1290) ? pw[(long)row * 1290 + cc] : 0.0f;
        splitf(v, h8[j], l8[j]);
    }
    *(bf16x8*)(hi + i) = *(const bf16x8*)h8;
    *(bf16x8*)(lo + i) = *(const bf16x8*)l8;
}

// patch input: x (B,129,5000) -> patch-major hi/lo bf16 (2000 x PK), K = c*10+kq
__global__ __launch_bounds__(256)
void xsplit_k(const float* __restrict__ x, unsigned short* __restrict__ xh,
              unsigned short* __restrict__ xl)
{
    int i = blockIdx.x * 256 + threadIdx.x;        // slot = m*164 + k8
    if (i >= PM * (PK / 8)) return;
    int m = i / (PK / 8), k8 = i - m * (PK / 8);
    int b = m / 500, tp = m - b * 500;
    const float* xb = x + (long)b * 129 * 5000 + tp * 10;
    unsigned short h8[8], l8[8];
#pragma unroll
    for (int e = 0; e < 8; ++e) {
        int k = k8 * 8 + e;
        int c = k / 10, kq = k - c * 10;
        float v = (k < 1290) ? xb[(long)c * 5000 + kq] : 0.0f;
        splitf(v, h8[e], l8[e]);
    }
    long o = (long)m * PK + k8 * 8;
    *(bf16x8*)(xh + o) = *(const bf16x8*)h8;
    *(bf16x8*)(xl + o) = *(const bf16x8*)l8;
}

// grid (B), 64 threads: write cls row
__global__ __launch_bounds__(64)
void cls_k(const float* __restrict__ cls, float* __restrict__ h)
{
    int b = blockIdx.x, lane = threadIdx.x;
    ((float4*)(h + (long)b * S * DM))[lane] = ((const float4*)cls)[lane];
}

// ---------------- layernorm over 256: one wave per row ----------------
template<bool SPLIT>
__global__ __launch_bounds__(64)
void ln_k(const float* __restrict__ hin, const float* __restrict__ g,
          const float* __restrict__ be, float* __restrict__ outf,
          unsigned short* __restrict__ oh, unsigned short* __restrict__ ol, int rowMul)
{
    long hr = (long)blockIdx.x * rowMul;
    int lane = threadIdx.x;
    float4 v = ((const float4*)(hin + hr * DM))[lane];
    float s = v.x + v.y + v.z + v.w;
    float q = v.x * v.x + v.y * v.y + v.z * v.z + v.w * v.w;
#pragma unroll
    for (int off = 32; off; off >>= 1) { s += __shfl_xor(s, off); q += __shfl_xor(q, off); }
    float mean = s * (1.0f / DM);
    float var  = q * (1.0f / DM) - mean * mean;
    float rs = rsqrtf(var + 1e-5f);
    float4 gg = ((const float4*)g)[lane];
    float4 bb = ((const float4*)be)[lane];
    float o[4];
    o[0] = (v.x - mean) * rs * gg.x + bb.x;
    o[1] = (v.y - mean) * rs * gg.y + bb.y;
    o[2] = (v.z - mean) * rs * gg.z + bb.z;
    o[3] = (v.w - mean) * rs * gg.w + bb.w;
    if constexpr (SPLIT) {
        unsigned short h4[4], l4[4];
#pragma unroll
        for (int j = 0; j < 4; ++j) splitf(o[j], h4[j], l4[j]);
        long idx = (long)blockIdx.x * DM + lane * 4;
        *(bf16x4*)(oh + idx) = *(const bf16x4*)h4;
        *(bf16x4*)(ol + idx) = *(const bf16x4*)l4;
    } else {
        ((float4*)(outf + (long)blockIdx.x * DM))[lane] = make_float4(o[0], o[1], o[2], o[3]);
    }
}

// ---------------- bf16x3 MFMA GEMM with pre-split hi/lo inputs ----------------
// C[m,n] = sum_k A[m,k]*W[n,k]; BK=32, 4 waves (2x2).
// EPI: 0=plain fp32 store, 2=gate-cat (bf16 hi/lo out + flip + silu gate),
//      3=residual add, 4=bias + patch-scatter
template<int BM, int BN, int EPI>
__global__ __launch_bounds__(256, (BM == 64 ? 4 : 3))
void mgemm_k(const unsigned short* __restrict__ Ah0, const unsigned short* __restrict__ Al0,
             const unsigned short* __restrict__ Ah1, const unsigned short* __restrict__ Al1,
             int lda,
             const unsigned short* __restrict__ Wh0, const unsigned short* __restrict__ Wl0,
             const unsigned short* __restrict__ Wh1, const unsigned short* __restrict__ Wl1,
             int ldw,
             float* __restrict__ Cout, long cStrideZ, int ldc,
             const float* __restrict__ resid,
             unsigned short* __restrict__ Oh, unsigned short* __restrict__ Ol,
             int M, int N, int K)
{
    constexpr int MI = BM / 32;
    constexpr int NJ = BN / 32;
    constexpr int LDAs = 40;
    constexpr int TOT = BM * 2 + BN * 2;   // staging slots (16 shorts each)

    __shared__ unsigned short sm[(2 * BM + 2 * BN) * LDAs];
    unsigned short* Ah_s = sm;
    unsigned short* Al_s = sm + BM * LDAs;
    unsigned short* Wh_s = sm + 2 * BM * LDAs;
    unsigned short* Wl_s = sm + 2 * BM * LDAs + BN * LDAs;

    const int dir = blockIdx.z;
    const unsigned short* __restrict__ A_h = dir ? Ah1 : Ah0;
    const unsigned short* __restrict__ A_l = dir ? Al1 : Al0;
    const unsigned short* __restrict__ W_h = dir ? Wh1 : Wh0;
    const unsigned short* __restrict__ W_l = dir ? Wl1 : Wl0;
    const int tid = threadIdx.x;
    const int lane = tid & 63;
    const int wave = tid >> 6;
    const int wr = wave >> 1, wc = wave & 1;
    const int m0 = blockIdx.x * BM, n0 = blockIdx.y * BN;
    const int kl = lane >> 4, rl = lane & 15;

    f32x4 acc[MI][NJ];
#pragma unroll
    for (int i = 0; i < MI; ++i)
#pragma unroll
        for (int j = 0; j < NJ; ++j) acc[i][j] = (f32x4){0.f, 0.f, 0.f, 0.f};

    const bf16x8 zv = {0, 0, 0, 0, 0, 0, 0, 0};

    for (int k0 = 0; k0 < K; k0 += 32) {
#pragma unroll
        for (int s = tid; s < TOT; s += 256) {
            if (s < BM * 2) {
                int row = s >> 1, cs = (s & 1) * 16;
                bool ok = (m0 + row) < M;
                long gi = (long)(m0 + row) * lda + k0 + cs;
                bf16x8 h0 = zv, h1 = zv, l0 = zv, l1 = zv;
                if (ok) {
                    h0 = *(const bf16x8*)(A_h + gi);
                    h1 = *(const bf16x8*)(A_h + gi + 8);
                    l0 = *(const bf16x8*)(A_l + gi);
                    l1 = *(const bf16x8*)(A_l + gi + 8);
                }
                *(bf16x8*)(Ah_s + row * LDAs + cs) = h0;
                *(bf16x8*)(Ah_s + row * LDAs + cs + 8) = h1;
                *(bf16x8*)(Al_s + row * LDAs + cs) = l0;
                *(bf16x8*)(Al_s + row * LDAs + cs + 8) = l1;
            } else {
                int s2 = s - BM * 2;
                int row = s2 >> 1, cs = (s2 & 1) * 16;
                long gi = (long)(n0 + row) * ldw + k0 + cs;
                *(bf16x8*)(Wh_s + row * LDAs + cs)     = *(const bf16x8*)(W_h + gi);
                *(bf16x8*)(Wh_s + row * LDAs + cs + 8) = *(const bf16x8*)(W_h + gi + 8);
                *(bf16x8*)(Wl_s + row * LDAs + cs)     = *(const bf16x8*)(W_l + gi);
                *(bf16x8*)(Wl_s + row * LDAs + cs + 8) = *(const bf16x8*)(W_l + gi + 8);
            }
        }
        __syncthreads();

        bf16x8 ah[MI], al[MI], wh[NJ], wl[NJ];
#pragma unroll
        for (int i = 0; i < MI; ++i) {
            int r = wr * (BM / 2) + i * 16 + rl;
            ah[i] = *(const bf16x8*)&Ah_s[r * LDAs + kl * 8];
            al[i] = *(const bf16x8*)&Al_s[r * LDAs + kl * 8];
        }
#pragma unroll
        for (int j = 0; j < NJ; ++j) {
            int r = wc * (BN / 2) + j * 16 + rl;
            wh[j] = *(const bf16x8*)&Wh_s[r * LDAs + kl * 8];
            wl[j] = *(const bf16x8*)&Wl_s[r * LDAs + kl * 8];
        }
#pragma unroll
        for (int i = 0; i < MI; ++i)
#pragma unroll
            for (int j = 0; j < NJ; ++j) {
                acc[i][j] = __builtin_amdgcn_mfma_f32_16x16x32_bf16(ah[i], wl[j], acc[i][j], 0, 0, 0);
                acc[i][j] = __builtin_amdgcn_mfma_f32_16x16x32_bf16(al[i], wh[j], acc[i][j], 0, 0, 0);
                acc[i][j] = __builtin_amdgcn_mfma_f32_16x16x32_bf16(ah[i], wh[j], acc[i][j], 0, 0, 0);
            }
        __syncthreads();
    }

    float* C = Cout + (long)dir * cStrideZ;
#pragma unroll
    for (int i = 0; i < MI; ++i) {
#pragma unroll
        for (int j = 0; j < NJ; ++j) {
            int rbase = m0 + wr * (BM / 2) + i * 16 + (lane >> 4) * 4;
            int colg = n0 + wc * (BN / 2) + j * 16 + (lane & 15);
#pragma unroll
            for (int r = 0; r < 4; ++r) {
                int rowg = rbase + r;
                if (rowg >= M) continue;
                float val = acc[i][j][r];
                if constexpr (EPI == 0) {
                    C[(long)rowg * ldc + colg] = val;
                } else if constexpr (EPI == 2) {
                    int bb = rowg / S;
                    int t  = rowg - bb * S;
                    long rt = dir ? (long)(bb * S + (S - 1 - t)) : (long)rowg;
                    float g = resid[rt * DH + DI + colg];
                    float o = val * silu_f(g);
                    unsigned short hh, ll;
                    splitf(o, hh, ll);
                    Oh[rt * DH + (dir ? DI : 0) + colg] = hh;
                    Ol[rt * DH + (dir ? DI : 0) + colg] = ll;
                } else if constexpr (EPI == 3) {
                    C[(long)rowg * ldc + colg] = val + resid[(long)rowg * ldc + colg];
                } else {   // EPI == 4: bias + scatter to token rows (skip cls)
                    int bb = rowg / 500;
                    int tt = rowg - bb * 500;
                    Cout[(long)(bb * S + 1 + tt) * ldc + colg] = val + resid[colg];
                }
            }
        }
    }
}

// ---------------- fp32 GEMM for small shapes (xp N=64, dtw K=32) ----------------
template<int EPI>
__global__ __launch_bounds__(256)
void gemm_k(const float* __restrict__ A0, const float* __restrict__ A1, int lda,
            const float* __restrict__ W0, const float* __restrict__ W1,
            const float* __restrict__ b0, const float* __restrict__ b1,
            float* __restrict__ Cout, long cStrideZ, int ldc,
            int M, int N, int K)
{
    const int dir = blockIdx.z;
    const float* __restrict__ A = dir ? A1 : A0;
    const float* __restrict__ W = dir ? W1 : W0;
    __shared__ float As[16][64];
    __shared__ float Ws[16][64];
    const int tid = threadIdx.x;
    const int tx = tid & 15, ty = tid >> 4;
    const int m0 = blockIdx.x * 64, n0 = blockIdx.y * 64;
    const int arow = tid >> 2;
    const int acol = (tid & 3) * 4;
    float acc[4][4] = {};

    for (int k0 = 0; k0 < K; k0 += 16) {
        {
            int row = m0 + arow;
            float4 va = make_float4(0.f, 0.f, 0.f, 0.f);
            if (row < M) va = *(const float4*)(A + (long)row * lda + k0 + acol);
            As[acol + 0][arow] = va.x; As[acol + 1][arow] = va.y;
            As[acol + 2][arow] = va.z; As[acol + 3][arow] = va.w;
            float4 vw = *(const float4*)(W + (long)(n0 + arow) * K + k0 + acol);
            Ws[acol + 0][arow] = vw.x; Ws[acol + 1][arow] = vw.y;
            Ws[acol + 2][arow] = vw.z; Ws[acol + 3][arow] = vw.w;
        }
        __syncthreads();
#pragma unroll
        for (int kk = 0; kk < 16; ++kk) {
            float4 av = *(const float4*)&As[kk][ty * 4];
            float4 wv = *(const float4*)&Ws[kk][tx * 4];
            float a[4] = {av.x, av.y, av.z, av.w};
            float w[4] = {wv.x, wv.y, wv.z, wv.w};
#pragma unroll
            for (int i = 0; i < 4; ++i)
#pragma unroll
                for (int j = 0; j < 4; ++j)
                    acc[i][j] = fmaf(a[i], w[j], acc[i][j]);
        }
        __syncthreads();
    }

    const float* bias = dir ? b1 : b0;
    float* C = Cout + (long)dir * cStrideZ;
#pragma unroll
    for (int i = 0; i < 4; ++i) {
        int row = m0 + ty * 4 + i;
        if (row >= M) continue;
        int col = n0 + tx * 4;
        if constexpr (EPI == 0) {
            float4 v = make_float4(acc[i][0], acc[i][1], acc[i][2], acc[i][3]);
            *(float4*)(C + (long)row * ldc + col) = v;
        } else {
            float4 b4 = *(const float4*)(bias + col);
            float4 v;
            v.x = softplus_f(acc[i][0] + b4.x);
            v.y = softplus_f(acc[i][1] + b4.y);
            v.z = softplus_f(acc[i][2] + b4.z);
            v.w = softplus_f(acc[i][3] + b4.w);
            *(float4*)(C + (long)row * ldc + col) = v;
        }
    }
}

// ---------------- causal depthwise conv (K=4) + silu ----------------
template<int MODE>
__global__ __launch_bounds__(256)
void conv_k(const float* __restrict__ in0, const float* __restrict__ in1,
            const float* __restrict__ cw0, const float* __restrict__ cw1,
            const float* __restrict__ cb0, const float* __restrict__ cb1,
            float* __restrict__ outf, long outStrideZ,
            unsigned short* __restrict__ oh, unsigned short* __restrict__ ol,
            unsigned short* __restrict__ orh, unsigned short* __restrict__ orl)
{
    const int dir = blockIdx.z;
    const float* __restrict__ in = dir ? in1 : in0;
    const float* __restrict__ cw = dir ? cw1 : cw0;
    const float* __restrict__ cb = dir ? cb1 : cb0;
    int idx = blockIdx.x * 256 + threadIdx.x;
    if (idx >= T * DI) return;
    int d = idx & (DI - 1);
    int r = idx >> 9;
    int b = r / S, t = r - b * S;
    float acc = cb[d];
#pragma unroll
    for (int k = 0; k < 4; ++k) {
        int tt = t - 3 + k;
        if (tt >= 0) acc = fmaf(cw[d * 4 + k], in[(long)(b * S + tt) * DH + d], acc);
    }
    acc = silu_f(acc);
    if constexpr (MODE == 0) {
        unsigned short hh, ll;
        splitf(acc, hh, ll);
        long i0 = (long)r * DI + d;
        long i1 = (long)(b * S + (S - 1 - t)) * DI + d;
        oh[i0] = hh;  ol[i0] = ll;
        orh[i1] = hh; orl[i1] = ll;
    } else {
        (outf + (long)dir * outStrideZ)[(long)r * DI + d] = acc;
    }
}

// ---------------- chunked parallel selective scan ----------------
__global__ __launch_bounds__(512)
void scanA_k(const float* __restrict__ delta, const float* __restrict__ dtBC,
             const float* __restrict__ u,
             const float* __restrict__ Al0, const float* __restrict__ Al1,
             float* __restrict__ Pb, float* __restrict__ Qb)
{
    __shared__ float B_s[CS * 16];
    const int b = blockIdx.x, c = blockIdx.y, dir = blockIdx.z;
    const int d = threadIdx.x;
    const int c0 = c * CS;
    const int tt = min(CS, S - c0);

    const float* dl  = delta + (long)dir * T * DI + (long)b * S * DI;
    const float* bcp = dtBC  + (long)dir * T * 64 + (long)b * S * 64;
    const float* uu  = u     + (long)dir * T * DI + (long)b * S * DI;

    if (threadIdx.x < CS * 16) {
        int t = threadIdx.x >> 4, n = threadIdx.x & 15;
        B_s[threadIdx.x] = (t < tt) ? bcp[(long)(c0 + t) * 64 + RDT + n] : 0.f;
    }
    __syncthreads();

    const float* Al = dir ? Al1 : Al0;
    float A2[16], Pv[16], Qv[16];
#pragma unroll
    for (int i = 0; i < 4; ++i) {
        float4 a4 = *(const float4*)(Al + (long)d * NST + 4 * i);
        A2[4 * i + 0] = -__expf(a4.x);
        A2[4 * i + 1] = -__expf(a4.y);
        A2[4 * i + 2] = -__expf(a4.z);
        A2[4 * i + 3] = -__expf(a4.w);
    }
#pragma unroll
    for (int n = 0; n < 16; ++n) { Pv[n] = 1.0f; Qv[n] = 0.0f; }

#pragma unroll 2
    for (int t = 0; t < tt; ++t) {
        float dv = dl[(long)(c0 + t) * DI + d];
        float uv = uu[(long)(c0 + t) * DI + d];
        float dvu = dv * uv;
#pragma unroll
        for (int n = 0; n < 16; ++n) {
            float a = __expf(dv * A2[n]);
            Pv[n] *= a;
            Qv[n] = fmaf(a, Qv[n], dvu * B_s[t * 16 + n]);
        }
    }

    long st0 = ((long)(dir * B + b) * DI + d) * NST;
    long co  = (long)c * NSTATE;
#pragma unroll
    for (int i = 0; i < 4; ++i) {
        *(float4*)(Pb + co + st0 + 4 * i) =
            make_float4(Pv[4 * i], Pv[4 * i + 1], Pv[4 * i + 2], Pv[4 * i + 3]);
        *(float4*)(Qb + co + st0 + 4 * i) =
            make_float4(Qv[4 * i], Qv[4 * i + 1], Qv[4 * i + 2], Qv[4 * i + 3]);
    }
}

__global__ __launch_bounds__(256)
void scanB_k(const float* __restrict__ Pb, const float* __restrict__ Qb,
             float* __restrict__ h0)
{
    const int st = blockIdx.x * 256 + threadIdx.x;
    float Pv[NCH], Qv[NCH];
#pragma unroll
    for (int c = 0; c < NCH; ++c) {
        Pv[c] = Pb[(long)c * NSTATE + st];
        Qv[c] = Qb[(long)c * NSTATE + st];
    }
    float h = 0.0f;
#pragma unroll
    for (int c = 0; c < NCH; ++c) {
        h0[(long)c * NSTATE + st] = h;
        h = fmaf(Pv[c], h, Qv[c]);
    }
}

// Phase C: replay chunk; emits p as bf16 hi/lo (feeds ow MFMA GEMM).
__global__ __launch_bounds__(512)
void scanC_k(const float* __restrict__ delta, const float* __restrict__ dtBC,
             const float* __restrict__ u, const float* __restrict__ xmz,
             const float* __restrict__ Al0, const float* __restrict__ Al1,
             const float* __restrict__ D0, const float* __restrict__ D1,
             const float* __restrict__ h0,
             unsigned short* __restrict__ ph, unsigned short* __restrict__ pl)
{
    __shared__ float BC_s[CS * 32];
    const int b = blockIdx.x, c = blockIdx.y, dir = blockIdx.z;
    const int d = threadIdx.x;
    const int c0 = c * CS;
    const int tt = min(CS, S - c0);

    const float* dl  = delta + (long)dir * T * DI + (long)b * S * DI;
    const float* bcp = dtBC  + (long)dir * T * 64 + (long)b * S * 64;
    const float* uu  = u     + (long)dir * T * DI + (long)b * S * DI;
    const float* zz  = xmz   + (long)dir * T * DH + (long)b * S * DH + DI;
    unsigned short* poh = ph + (long)dir * T * DI + (long)b * S * DI;
    unsigned short* pol = pl + (long)dir * T * DI + (long)b * S * DI;

    {
        int t = threadIdx.x >> 5, j = threadIdx.x & 31;
        BC_s[threadIdx.x] = (t < tt) ? bcp[(long)(c0 + t) * 64 + RDT + j] : 0.f;
    }
    __syncthreads();

    const float* Al = dir ? Al1 : Al0;
    float A2[16], hv[16];
#pragma unroll
    for (int i = 0; i < 4; ++i) {
        float4 a4 = *(const float4*)(Al + (long)d * NST + 4 * i);
        A2[4 * i + 0] = -__expf(a4.x);
        A2[4 * i + 1] = -__expf(a4.y);
        A2[4 * i + 2] = -__expf(a4.z);
        A2[4 * i + 3] = -__expf(a4.w);
    }
    long st0 = ((long)(dir * B + b) * DI + d) * NST;
#pragma unroll
    for (int i = 0; i < 4; ++i) {
        float4 h4 = *(const float4*)(h0 + (long)c * NSTATE + st0 + 4 * i);
        hv[4 * i + 0] = h4.x; hv[4 * i + 1] = h4.y;
        hv[4 * i + 2] = h4.z; hv[4 * i + 3] = h4.w;
    }
    const float Dp = (dir ? D1 : D0)[d];

#pragma unroll 2
    for (int t = 0; t < tt; ++t) {
        float dv = dl[(long)(c0 + t) * DI + d];
        float uv = uu[(long)(c0 + t) * DI + d];
        float zv = zz[(long)(c0 + t) * DH + d];
        float dvu = dv * uv;
        float y = 0.0f;
#pragma unroll
        for (int n = 0; n < 16; ++n) {
            float a = __expf(dv * A2[n]);
            hv[n] = fmaf(a, hv[n], dvu * BC_s[t * 32 + n]);
            y = fmaf(hv[n], BC_s[t * 32 + 16 + n], y);
        }
        float sz = zv / (1.0f + __expf(-zv));
        float o = (y + uv * Dp) * sz;
        unsigned short hh, ll;
        splitf(o, hh, ll);
        poh[(long)(c0 + t) * DI + d] = hh;
        pol[(long)(c0 + t) * DI + d] = ll;
    }
}

// ---------------- host orchestration ----------------
extern "C" void kernel_launch(void* const* d_in, const int* in_sizes, int n_in,
                              void* d_out, int out_size, void* d_ws, size_t ws_size,
                              hipStream_t stream)
{
    (void)in_sizes; (void)n_in; (void)out_size; (void)ws_size;
    const float* x        = (const float*)d_in[0];
    const float* patch_w  = (const float*)d_in[1];
    const float* patch_b  = (const float*)d_in[2];
    const float* cls_tok  = (const float*)d_in[3];
    const float* ln_g     = (const float*)d_in[4];
    const float* ln_b     = (const float*)d_in[5];
    const float* in_w     = (const float*)d_in[6];
    const float* cw       = (const float*)d_in[7];
    const float* cb       = (const float*)d_in[8];
    const float* out_w    = (const float*)d_in[9];
    const float* fn_g     = (const float*)d_in[10];
    const float* fn_b     = (const float*)d_in[11];
    const float* mf_in    = (const float*)d_in[12];
    const float* mf_cw    = (const float*)d_in[13];
    const float* mf_cb    = (const float*)d_in[14];
    const float* mf_xp    = (const float*)d_in[15];
    const float* mf_dtw   = (const float*)d_in[16];
    const float* mf_dtb   = (const float*)d_in[17];
    const float* mf_Al    = (const float*)d_in[18];
    const float* mf_D     = (const float*)d_in[19];
    const float* mf_ow    = (const float*)d_in[20];
    const float* mb_in    = (const float*)d_in[21];
    const float* mb_cw    = (const float*)d_in[22];
    const float* mb_cb    = (const float*)d_in[23];
    const float* mb_xp    = (const float*)d_in[24];
    const float* mb_dtw   = (const float*)d_in[25];
    const float* mb_dtb   = (const float*)d_in[26];
    const float* mb_Al    = (const float*)d_in[27];
    const float* mb_D     = (const float*)d_in[28];
    const float* mb_ow    = (const float*)d_in[29];

    float* ws = (float*)d_ws;
    float* h      = ws;                    // T*DM
    float* xcres  = h     + (long)T * DM;  // T*DH
    float* xmz    = xcres + (long)T * DH;  // 2*T*DH
    float* u      = xmz   + 2L * T * DH;   // 2*T*DI
    float* dtBC   = u     + 2L * T * DI;   // 2*T*64
    float* delta  = dtBC  + 2L * T * 64;   // 2*T*DI
    float* Pb     = delta + 2L * T * DI;   // NCH*NSTATE
    float* Qb     = Pb    + (long)NCH * NSTATE;
    float* h0b    = Qb    + (long)NCH * NSTATE;
    unsigned short* us = (unsigned short*)(h0b + (long)NCH * NSTATE);
    unsigned short* xnh  = us;                       // T*DM
    unsigned short* xnl  = xnh + (long)T * DM;
    unsigned short* xch  = xnl + (long)T * DM;       // T*DI
    unsigned short* xcl  = xch + (long)T * DI;
    unsigned short* xrvh = xcl + (long)T * DI;
    unsigned short* xrvl = xrvh + (long)T * DI;
    unsigned short* ph   = xrvl + (long)T * DI;      // 2*T*DI
    unsigned short* pl   = ph   + 2L * T * DI;
    unsigned short* ych  = pl   + 2L * T * DI;       // T*DH
    unsigned short* ycl  = ych  + (long)T * DH;
    unsigned short* WH   = ycl  + (long)T * DH;      // 2097152 (per-layer, reused)
    unsigned short* WL   = WH   + WSEGT;
    unsigned short* PWH  = WL   + WSEGT;             // 256*PK
    unsigned short* PWL  = PWH  + 256L * PK;
    unsigned short* XTH  = PWL  + 256L * PK;         // PM*PK
    unsigned short* XTL  = XTH  + (long)PM * PK;

    const long o_inw = 0, o_fin = WSEG1, o_bin = WSEG2, o_fow = WSEG3,
               o_bow = WSEG4, o_oww = WSEG5;

    // patch embed: pre-split weights + input, MFMA GEMM with scatter, cls row
    pwsplit_k<<<dim3(256 * PK / 2048), 256, 0, stream>>>(patch_w, PWH, PWL);
    xsplit_k<<<dim3((PM * (PK / 8) + 255) / 256), 256, 0, stream>>>(x, XTH, XTL);
    mgemm_k<64, 32, 4><<<dim3((PM + 63) / 64, DM / 32, 1), 256, 0, stream>>>(
        XTH, XTL, XTH, XTL, PK, PWH, PWL, PWH, PWL, PK,
        h, 0, DM, patch_b, nullptr, nullptr, PM, DM, PK);
    cls_k<<<dim3(B), 64, 0, stream>>>(cls_tok, h);

    constexpr int GM64  = (T + 63) / 64;    // 32
    constexpr int GM128 = (T + 127) / 128;  // 16

    for (int l = 0; l < LAYERS; ++l) {
        const float* lng = ln_g + (long)l * DM;
        const float* lnb = ln_b + (long)l * DM;
        const float* inw = in_w + (long)l * DH * DM;
        const float* cwl = cw   + (long)l * DI * 4;
        const float* cbl = cb   + (long)l * DI;
        const float* oww = out_w + (long)l * DM * DH;
        const float* fin = mf_in + (long)l * DH * DI;
        const float* bin = mb_in + (long)l * DH * DI;
        const float* fcw = mf_cw + (long)l * DI * 4;
        const float* bcw = mb_cw + (long)l * DI * 4;
        const float* fcb = mf_cb + (long)l * DI;
        const float* bcb = mb_cb + (long)l * DI;
        const float* fxp = mf_xp + (long)l * (RDT + 2 * NST) * DI;
        const float* bxp = mb_xp + (long)l * (RDT + 2 * NST) * DI;
        const float* fdw = mf_dtw + (long)l * DI * RDT;
        const float* bdw = mb_dtw + (long)l * DI * RDT;
        const float* fdb = mf_dtb + (long)l * DI;
        const float* bdb = mb_dtb + (long)l * DI;
        const float* fAl = mf_Al + (long)l * DI * NST;
        const float* bAl = mb_Al + (long)l * DI * NST;
        const float* fD  = mf_D  + (long)l * DI;
        const float* bD  = mb_D  + (long)l * DI;
        const float* fow = mf_ow + (long)l * DI * DI;
        const float* bow = mb_ow + (long)l * DI * DI;

        // split this layer's big weights to hi/lo bf16
        lsplit_k<<<dim3(WSEGT / 2048), 256, 0, stream>>>(inw, fin, bin, fow, bow, oww, WH, WL);

        // xn(hi/lo) = LN(h)
        ln_k<true><<<dim3(T), 64, 0, stream>>>(h, lng, lnb, nullptr, xnh, xnl, 1);
        // xcres = xn @ in_w^T  (T x 1024)   grid 16x16 = 256 blocks
        mgemm_k<128, 64, 0><<<dim3(GM128, DH / 64, 1), 256, 0, stream>>>(
            xnh, xnl, xnh, xnl, DM, WH + o_inw, WL + o_inw, WH + o_inw, WL + o_inw, DM,
            xcres, 0, DH, nullptr, nullptr, nullptr, T, DH, DM);
        // xc(hi/lo) = silu(dwconv(xcres[:, :512])), + time-reversed copy
        conv_k<0><<<dim3(T * DI / 256, 1, 1), 256, 0, stream>>>(
            xcres, xcres, cwl, cwl, cbl, cbl, nullptr, 0, xch, xcl, xrvh, xrvl);
        // xmz[dir] = (xc|xcrev) @ m{f,b}_in^T  (T x 1024)  grid 16x16x2 = 512 blocks
        mgemm_k<128, 64, 0><<<dim3(GM128, DH / 64, 2), 256, 0, stream>>>(
            xch, xcl, xrvh, xrvl, DI, WH + o_fin, WL + o_fin, WH + o_bin, WL + o_bin, DI,
            xmz, (long)T * DH, DH, nullptr, nullptr, nullptr, T, DH, DI);
        // u[dir] = silu(dwconv(xmz[dir][:, :512]))  (fp32, scan needs it)
        conv_k<1><<<dim3(T * DI / 256, 1, 2), 256, 0, stream>>>(
            xmz, xmz + (long)T * DH, fcw, bcw, fcb, bcb, u, (long)T * DI,
            nullptr, nullptr, nullptr, nullptr);
        // dtBC[dir] = u[dir] @ xp^T  (T x 64), fp32
        gemm_k<0><<<dim3(GM64, 1, 2), 256, 0, stream>>>(
            u, u + (long)T * DI, DI, fxp, bxp, nullptr, nullptr, dtBC, (long)T * 64, 64,
            T, 64, DI);
        // delta[dir] = softplus(dt @ dtw^T + dtb)  (T x 512), fp32 (K=32)
        gemm_k<1><<<dim3(GM64, DI / 64, 2), 256, 0, stream>>>(
            dtBC, dtBC + (long)T * 64, 64, fdw, bdw, fdb, bdb, delta, (long)T * DI, DI,
            T, DI, RDT);
        // chunked parallel scan (C emits p as hi/lo bf16)
        scanA_k<<<dim3(B, NCH, 2), 512, 0, stream>>>(delta, dtBC, u, fAl, bAl, Pb, Qb);
        scanB_k<<<dim3(NSTATE / 256), 256, 0, stream>>>(Pb, Qb, h0b);
        scanC_k<<<dim3(B, NCH, 2), 512, 0, stream>>>(
            delta, dtBC, u, xmz, fAl, bAl, fD, bD, h0b, ph, pl);
        // ycat(hi/lo) = gated out-proj of both dirs  grid 16x8x2 = 256 blocks
        mgemm_k<128, 64, 2><<<dim3(GM128, DI / 64, 2), 256, 0, stream>>>(
            ph, pl, ph + (long)T * DI, pl + (long)T * DI, DI,
            WH + o_fow, WL + o_fow, WH + o_bow, WL + o_bow, DI,
            nullptr, 0, DH, xcres, ych, ycl, T, DI, DI);
        // h = ycat @ out_w^T + h   grid 32x8 = 256 blocks
        mgemm_k<64, 32, 3><<<dim3(GM64, DM / 32, 1), 256, 0, stream>>>(
            ych, ycl, ych, ycl, DH, WH + o_oww, WL + o_oww, WH + o_oww, WL + o_oww, DH,
            h, 0, DM, h, nullptr, nullptr, T, DM, DH);
    }

    // final LN on cls rows only -> d_out (4 x 256)
    ln_k<false><<<dim3(B), 64, 0, stream>>>(h, fn_g, fn_b, (float*)d_out, nullptr, nullptr, S);
}